// Round 7
// baseline (1143.945 us; speedup 1.0000x reference)
//
#include <hip/hip_runtime.h>
#include <cstdint>
#include <math.h>

typedef _Float16 f16;
typedef __attribute__((ext_vector_type(4))) _Float16 f16x4;
typedef __attribute__((ext_vector_type(8))) _Float16 f16x8;
typedef __attribute__((ext_vector_type(4))) float f32x4;

// ---------------------------------------------------------------- helpers
__device__ inline void gload_lds16(const void* g, void* l) {
  auto gp = reinterpret_cast<const __attribute__((address_space(1))) uint32_t*>(
      reinterpret_cast<uintptr_t>(g));
  auto lp = reinterpret_cast<__attribute__((address_space(3))) uint32_t*>(
      reinterpret_cast<uintptr_t>(l));
  __builtin_amdgcn_global_load_lds(gp, lp, 16 /*bytes*/, 0, 0);
}

__device__ inline float wave_sum64(float v) {
#pragma unroll
  for (int m = 1; m < 64; m <<= 1) v += __shfl_xor(v, m);
  return v;
}

// ---------------------------------------------------------------- fp32 -> f16 convert
__global__ __launch_bounds__(256) void cvt_kernel(const float* __restrict__ src,
                                                  f16* __restrict__ dst, int n4) {
  int idx = blockIdx.x * blockDim.x + threadIdx.x;
  int stride = gridDim.x * blockDim.x;
  for (int i = idx; i < n4; i += stride) {
    float4 v = reinterpret_cast<const float4*>(src)[i];
    f16x4 h;
    h.x = (f16)v.x; h.y = (f16)v.y; h.z = (f16)v.z; h.w = (f16)v.w;
    reinterpret_cast<f16x4*>(dst)[i] = h;
  }
}

// ---------------------------------------------------------------- GEMM  C[M][N] = A[M][K] * B[N][K]^T
// 128x128 tile, BK=32, 4 waves (each a 64x64 quadrant), m97 structure + XCD swizzle.
// EPI==0: plain fp32 C.  EPI==1: fused RMS-norm (per 128-col head row) -> f16 Ch,
// with attention scale * log2e folded (Q path).
template <bool MB, int EPI>
__global__ __launch_bounds__(256, 2) void gemm_bt_f16(const f16* __restrict__ A,
                                                      const f16* __restrict__ Bw,
                                                      float* __restrict__ C,
                                                      f16* __restrict__ Ch,
                                                      const float* __restrict__ wvec,
                                                      int M, int N, int K) {
  __shared__ f16 As[2][128][32];
  __shared__ f16 Bs[2][128][32];
  const int tid = threadIdx.x;
  const int l = tid & 63, w = tid >> 6;
  const int lq = l & 15, lk = l >> 4;
  const int wr = w >> 1, wc = w & 1;
  // XCD-aware bijective swizzle (nwg % 8 == 0 for all our grids)
  const int nwg = gridDim.x * gridDim.y;
  const int p = blockIdx.y * gridDim.x + blockIdx.x;
  const int L = (p & 7) * (nwg >> 3) + (p >> 3);
  const int bx = L % gridDim.x, by = L / gridDim.x;
  const int brow = by * 128, bcol = bx * 128;
  const int srow = w * 16 + (l >> 2);   // staging row (+j*64)
  const int scol = (l & 3) * 8;         // staging col in f16 elems
  const int KT = K >> 5;

  f32x4 acc[4][4];
  f32x4 zf = {0.f, 0.f, 0.f, 0.f};
#pragma unroll
  for (int m = 0; m < 4; ++m)
#pragma unroll
    for (int n = 0; n < 4; ++n) acc[m][n] = zf;

  auto stage = [&](int kt, int buf) {
    const int k0 = kt * 32 + scol;
#pragma unroll
    for (int j = 0; j < 2; ++j) {
      int ra = brow + j * 64 + srow;
      if (MB) ra = (ra < M) ? ra : (M - 1);
      gload_lds16(A + (size_t)ra * K + k0,
                  (char*)(&As[buf][0][0]) + j * 4096 + w * 1024);
      int rb = bcol + j * 64 + srow;
      gload_lds16(Bw + (size_t)rb * K + k0,
                  (char*)(&Bs[buf][0][0]) + j * 4096 + w * 1024);
    }
  };

  stage(0, 0);
  for (int kt = 0; kt < KT; ++kt) {
    const int buf = kt & 1;
    __syncthreads();                 // drains vmcnt for stage(kt); also read/overwrite fence
    if (kt + 1 < KT) stage(kt + 1, buf ^ 1);  // prefetch overlaps this iter's compute
    f16x8 af[4], bf[4];
#pragma unroll
    for (int m = 0; m < 4; ++m)
      af[m] = *reinterpret_cast<const f16x8*>(&As[buf][wr * 64 + m * 16 + lq][lk * 8]);
#pragma unroll
    for (int n = 0; n < 4; ++n)
      bf[n] = *reinterpret_cast<const f16x8*>(&Bs[buf][wc * 64 + n * 16 + lq][lk * 8]);
#pragma unroll
    for (int m = 0; m < 4; ++m)
#pragma unroll
      for (int n = 0; n < 4; ++n)
        acc[m][n] = __builtin_amdgcn_mfma_f32_16x16x32_f16(af[m], bf[n], acc[m][n], 0, 0, 0);
  }

  if (EPI == 0) {
#pragma unroll
    for (int m = 0; m < 4; ++m) {
#pragma unroll
      for (int j = 0; j < 4; ++j) {
        int row = brow + wr * 64 + m * 16 + lk * 4 + j;
        if (MB && row >= M) continue;
        float* dst = C + (size_t)row * N + bcol + wc * 64 + lq;
#pragma unroll
        for (int n = 0; n < 4; ++n) dst[n * 16] = acc[m][n][j];
      }
    }
  } else {
    // fused RMS over the 128-col head row (block spans exactly one head)
    __syncthreads();                          // LDS reuse fence
    float* ssq = (float*)(&As[0][0][0]);      // [128][2] partial sums
#pragma unroll
    for (int m = 0; m < 4; ++m)
#pragma unroll
      for (int j = 0; j < 4; ++j) {
        int lr = wr * 64 + m * 16 + lk * 4 + j;
        float pp = 0.f;
#pragma unroll
        for (int n = 0; n < 4; ++n) pp += acc[m][n][j] * acc[m][n][j];
        pp += __shfl_xor(pp, 1);
        pp += __shfl_xor(pp, 2);
        pp += __shfl_xor(pp, 4);
        pp += __shfl_xor(pp, 8);
        if (lq == 0) ssq[lr * 2 + wc] = pp;
      }
    __syncthreads();
    float wv[4];
#pragma unroll
    for (int n = 0; n < 4; ++n) wv[n] = wvec[wc * 64 + n * 16 + lq];
#pragma unroll
    for (int m = 0; m < 4; ++m)
#pragma unroll
      for (int j = 0; j < 4; ++j) {
        int lr = wr * 64 + m * 16 + lk * 4 + j;
        float ss = ssq[lr * 2] + ssq[lr * 2 + 1];
        float rs = rsqrtf(ss * (1.0f / 128.0f) + 1e-5f) *
                   (0.08838834764831845f * 1.4426950408889634f);
        f16* dst = Ch + (size_t)(brow + lr) * N + bcol + wc * 64 + lq;
#pragma unroll
        for (int n = 0; n < 4; ++n) dst[n * 16] = (f16)(acc[m][n][j] * rs * wv[n]);
      }
  }
}

// ---------------------------------------------------------------- K RMS-norm + V transpose scatter
// KVraw [6404][2048] fp32 -> Kf [b][kvh][1664][128] f16 (normed), Vtf [b][kvh][128][1664] f16
__global__ __launch_bounds__(256) void kvscatter_kernel(const float* __restrict__ KVraw,
                                                        const float* __restrict__ wk,
                                                        f16* __restrict__ Kf,
                                                        f16* __restrict__ Vtf) {
  const int w = threadIdx.x >> 6, l = threadIdx.x & 63;
  const int gw = blockIdx.x * 4 + w;  // 0..51231
  const int r = gw >> 3, kvh = gw & 7;
  const int b = r / 1601, s = r - b * 1601;
  const float* kr = KVraw + (size_t)r * 2048 + kvh * 128;
  float2 kx = reinterpret_cast<const float2*>(kr)[l];
  float ss = wave_sum64(kx.x * kx.x + kx.y * kx.y);
  float rs = rsqrtf(ss * (1.0f / 128.0f) + 1e-5f);
  float2 wv = reinterpret_cast<const float2*>(wk)[l];
  union { f16 h[2]; unsigned u; } pk;
  pk.h[0] = (f16)(kx.x * rs * wv.x);
  pk.h[1] = (f16)(kx.y * rs * wv.y);
  reinterpret_cast<unsigned*>(Kf + ((size_t)(b * 8 + kvh) * 1664 + s) * 128)[l] = pk.u;
  const float* vr = kr + 1024;
  float2 vx = reinterpret_cast<const float2*>(vr)[l];
  f16* vcol = Vtf + ((size_t)(b * 8 + kvh) * 128 + l * 2) * 1664 + s;
  vcol[0] = (f16)vx.x;
  vcol[1664] = (f16)vx.y;
}

// ---------------------------------------------------------------- flash attention
// QBLK=64 (4 waves x 16 q rows), KVBLK=64. K double-buffered in LDS (32 KB) +
// per-wave P (8 KB) = 40 KB LDS. V^T read directly from global (L2-resident,
// 3.4 MB/XCD working set -- r4/r6 FETCH=30MB proves K/V stay in L2).
// (256,3): 170-reg cap; live state ~145 (o32+q16+s16/vb32+misc) -> no spill,
// 12 waves/CU (1.5x r6's 8). Counted vmcnt keeps K prefetch in flight.
__global__ __launch_bounds__(256, 3) void attn_kernel(const f16* __restrict__ Qf,
                                                      const f16* __restrict__ Kf,
                                                      const f16* __restrict__ Vtf,
                                                      f16* __restrict__ Oa) {
  __shared__ f16 Ksm[2][64][128];  // 32 KB dbuf, 256 B rows, XOR-swizzled
  __shared__ f16 Psm[4][16][64];   // 8 KB per-wave P (wave-private)
  const int p = blockIdx.x;              // 0..2047
  const int L = (p & 7) * 256 + (p >> 3);  // XCD-contiguous logical order
  const int qt = L & 15, h = (L >> 4) & 31, b = L >> 9;
  const int kvh = h >> 2;  // G = 4
  const int tid = threadIdx.x;
  const int l = tid & 63, w = tid >> 6;
  const int lq = l & 15, lk = l >> 4;

  // Q fragments in registers: wave w owns 16 q rows (qt*64 + w*16 ..)
  f16x8 qreg[4];
  const f16* Qbase = Qf + ((size_t)(b * 1024 + qt * 64 + w * 16)) * 4096 + h * 128;
#pragma unroll
  for (int ks = 0; ks < 4; ++ks)
    qreg[ks] = *reinterpret_cast<const f16x8*>(
        Qbase + (size_t)lq * 4096 + ks * 32 + lk * 8);

  const f16* Kb = Kf + (size_t)(b * 8 + kvh) * (1664 * 128);
  const f16* Vb = Vtf + (size_t)(b * 8 + kvh) * (128 * 1664);

  f32x4 o[8];
  f32x4 zf = {0.f, 0.f, 0.f, 0.f};
#pragma unroll
  for (int dn = 0; dn < 8; ++dn) o[dn] = zf;
  float mrow[4], lrow[4];  // per-lane partials (4 q rows: lk*4+j), reduced in epilogue
#pragma unroll
  for (int j = 0; j < 4; ++j) { mrow[j] = -1e30f; lrow[j] = 0.f; }

  char* Pw = (char*)(&Psm[w][0][0]);  // 16 rows x 128 B
  const int swzR = (lq & 7) << 4;

  auto stageK = [&](int t, int buf) {
#pragma unroll
    for (int i = 0; i < 4; ++i) {
      int row = w * 16 + i * 4 + lk;
      int cb = (lq * 16) ^ ((row & 7) << 4);
      gload_lds16(Kb + (size_t)(t * 64 + row) * 128 + (cb >> 1),
                  (char*)(&Ksm[buf][0][0]) + w * 4096 + i * 1024);
    }
  };

  stageK(0, 0);
  int cur = 0;
  for (int t = 0; t < 26; ++t) {
    if (t < 25) {
      stageK(t + 1, cur ^ 1);                        // 4 issues for tile t+1 in flight
      asm volatile("s_waitcnt vmcnt(4)" ::: "memory");   // own tile-t loads done
    } else {
      asm volatile("s_waitcnt vmcnt(0)" ::: "memory");
    }
    __builtin_amdgcn_s_barrier();                    // all waves' tile-t K staged

    // ---- S = Q K^T (fp32 accum), wave's 16 q rows x 64 kv cols
    f32x4 s[4];
#pragma unroll
    for (int kn = 0; kn < 4; ++kn) s[kn] = zf;
    __builtin_amdgcn_s_setprio(1);
#pragma unroll
    for (int ks = 0; ks < 4; ++ks) {
      f16x8 bf[4];
#pragma unroll
      for (int kn = 0; kn < 4; ++kn)
        bf[kn] = *reinterpret_cast<const f16x8*>(
            (char*)(&Ksm[cur][0][0]) + (kn * 16 + lq) * 256 + ((ks * 64 + lk * 16) ^ swzR));
#pragma unroll
      for (int kn = 0; kn < 4; ++kn)
        s[kn] = __builtin_amdgcn_mfma_f32_16x16x32_f16(qreg[ks], bf[kn], s[kn], 0, 0, 0);
    }
    __builtin_amdgcn_s_setprio(0);

    // ---- mask tail (valid kv < 1601; tile 25 covers 1600..1663 -> local < 1)
    if (t == 25) {
#pragma unroll
      for (int kn = 0; kn < 4; ++kn) {
        bool valid = (kn * 16 + lq) < 1;
#pragma unroll
        for (int j = 0; j < 4; ++j) s[kn][j] = valid ? s[kn][j] : -1e30f;
      }
    }

    // ---- online softmax (log2 domain), defer-rescale THR=8, per-lane lrow partials
#pragma unroll
    for (int j = 0; j < 4; ++j) {
      float mt = fmaxf(fmaxf(s[0][j], s[1][j]), fmaxf(s[2][j], s[3][j]));
      mt = fmaxf(mt, __shfl_xor(mt, 1));
      mt = fmaxf(mt, __shfl_xor(mt, 2));
      mt = fmaxf(mt, __shfl_xor(mt, 4));
      mt = fmaxf(mt, __shfl_xor(mt, 8));
      float mo = mrow[j];
      if (mt > mo + 8.0f) {           // rarely taken after tile 0
        float corr = exp2f(mo - mt);
        mrow[j] = mt;
        lrow[j] *= corr;
#pragma unroll
        for (int dn = 0; dn < 8; ++dn) o[dn][j] *= corr;
        mo = mt;
      }
      float rsum = 0.f;
#pragma unroll
      for (int kn = 0; kn < 4; ++kn) {
        float pv = exp2f(s[kn][j] - mo);
        s[kn][j] = pv;
        rsum += pv;
      }
      lrow[j] += rsum;                // per-lane partial; no shfl here
      int prow = lk * 4 + j;
      int swzW = (prow & 7) << 4;
#pragma unroll
      for (int kn = 0; kn < 4; ++kn)
        *reinterpret_cast<f16*>(Pw + prow * 128 + (((kn * 16 + lq) * 2) ^ swzW)) =
            (f16)s[kn][j];
    }

    // ---- O += P V   (A = P from own Psm; B = V^T direct from global, b128 L2 hits)
    __builtin_amdgcn_s_setprio(1);
#pragma unroll
    for (int c = 0; c < 2; ++c) {
      f16x8 pa = *reinterpret_cast<const f16x8*>(
          Pw + lq * 128 + ((c * 64 + lk * 16) ^ swzR));
      f16x8 vb[8];
#pragma unroll
      for (int dn = 0; dn < 8; ++dn)
        vb[dn] = *reinterpret_cast<const f16x8*>(
            Vb + (size_t)(dn * 16 + lq) * 1664 + t * 64 + c * 32 + lk * 8);
#pragma unroll
      for (int dn = 0; dn < 8; ++dn)
        o[dn] = __builtin_amdgcn_mfma_f32_16x16x32_f16(pa, vb[dn], o[dn], 0, 0, 0);
    }
    __builtin_amdgcn_s_setprio(0);
    __builtin_amdgcn_s_barrier();   // all QK^T reads of buf `cur` done before next stage
    cur ^= 1;
  }

  // ---- epilogue: reduce lrow partials across the 16-lane row group, then O/l
#pragma unroll
  for (int j = 0; j < 4; ++j) {
    float fl = lrow[j];
    fl += __shfl_xor(fl, 1);
    fl += __shfl_xor(fl, 2);
    fl += __shfl_xor(fl, 4);
    fl += __shfl_xor(fl, 8);
    float il = 1.0f / fl;
    int token = b * 1024 + qt * 64 + w * 16 + lk * 4 + j;
    f16* dst = Oa + (size_t)token * 4096 + h * 128;
#pragma unroll
    for (int dn = 0; dn < 8; ++dn) dst[dn * 16 + lq] = (f16)(o[dn][j] * il);
  }
}

// ---------------------------------------------------------------- launch
extern "C" void kernel_launch(void* const* d_in, const int* in_sizes, int n_in,
                              void* d_out, int out_size, void* d_ws, size_t ws_size,
                              hipStream_t stream) {
  const float* hidden = (const float*)d_in[0];  // [4,1024,4096]
  const float* cross  = (const float*)d_in[1];  // [4,1601,4096]
  const float* wqkv   = (const float*)d_in[2];  // [6144,4096]
  const float* wo     = (const float*)d_in[3];  // [4096,4096]
  const float* qw     = (const float*)d_in[4];  // [128]
  const float* kw     = (const float*)d_in[5];  // [128]

  char* ws = (char*)d_ws;
  // region A: hidden_f16 (33.55 MB) -> later attn_f16
  f16* hidden_h = (f16*)(ws + 0);
  f16* attn_h   = hidden_h;
  // region B: wqkv_f16 (50.33 MB)
  f16* wqkv_h = (f16*)(ws + 33554432);
  // region C: cross_f16 (52.46 MB) -> later K_f16 (13.63) + Vt_f16 (13.63)
  f16* cross_h = (f16*)(ws + 83886080);
  f16* k_h     = cross_h;
  f16* vt_h    = (f16*)(ws + 83886080 + 13631488);
  // region D: KVraw fp32 (52.46 MB) -> later wo_f16
  float* kvraw = (float*)(ws + 136347648);
  f16* wo_h    = (f16*)(ws + 136347648);
  // total ws use: 188,809,216 B
  // q_h lives in d_out (f16, 33.5 MB of the 67 MB fp32 buffer); it is fully
  // consumed by attn before the O-projection overwrites d_out.
  f16* q_h = (f16*)d_out;

  // 1) converts needed before projections
  cvt_kernel<<<2048, 256, 0, stream>>>(hidden, hidden_h, 16777216 / 4);
  cvt_kernel<<<2048, 256, 0, stream>>>(cross, cross_h, 26230784 / 4);
  cvt_kernel<<<2048, 256, 0, stream>>>(wqkv, wqkv_h, 25165824 / 4);
  // 2) KV projection: cross @ wqkv[4096:6144]^T -> KVraw [6404][2048]
  gemm_bt_f16<true, 0><<<dim3(16, 51), 256, 0, stream>>>(
      cross_h, wqkv_h + (size_t)4096 * 4096, kvraw, nullptr, nullptr, 6404, 2048, 4096);
  // 3) zero K/Vt pad cols (s in [1601,1664)), then scatter K (rms) + V (transpose)
  hipMemsetAsync(ws + 83886080, 0, 27262976, stream);
  kvscatter_kernel<<<12808, 256, 0, stream>>>(kvraw, kw, k_h, vt_h);
  // 4) wo convert (into dead KVraw region)
  cvt_kernel<<<2048, 256, 0, stream>>>(wo, wo_h, 16777216 / 4);
  // 5) Q projection with fused RMS-norm (+scale*log2e) -> f16 q_h (in d_out)
  gemm_bt_f16<false, 1><<<dim3(32, 32), 256, 0, stream>>>(
      hidden_h, wqkv_h, nullptr, q_h, qw, 4096, 4096, 4096);
  // 6) attention (QBLK=64, grid 2048, XCD-swizzled in-kernel)
  attn_kernel<<<2048, 256, 0, stream>>>(q_h, k_h, vt_h, attn_h);
  // 7) output projection -> d_out
  gemm_bt_f16<false, 0><<<dim3(32, 32), 256, 0, stream>>>(
      attn_h, wo_h, (float*)d_out, nullptr, nullptr, 4096, 4096, 4096);
}

// Round 8
// 830.491 us; speedup vs baseline: 1.3774x; 1.3774x over previous
//
#include <hip/hip_runtime.h>
#include <cstdint>
#include <math.h>

typedef _Float16 f16;
typedef __attribute__((ext_vector_type(4))) _Float16 f16x4;
typedef __attribute__((ext_vector_type(8))) _Float16 f16x8;
typedef __attribute__((ext_vector_type(4))) float f32x4;

// ---------------------------------------------------------------- helpers
__device__ inline void gload_lds16(const void* g, void* l) {
  auto gp = reinterpret_cast<const __attribute__((address_space(1))) uint32_t*>(
      reinterpret_cast<uintptr_t>(g));
  auto lp = reinterpret_cast<__attribute__((address_space(3))) uint32_t*>(
      reinterpret_cast<uintptr_t>(l));
  __builtin_amdgcn_global_load_lds(gp, lp, 16 /*bytes*/, 0, 0);
}

__device__ inline float wave_sum64(float v) {
#pragma unroll
  for (int m = 1; m < 64; m <<= 1) v += __shfl_xor(v, m);
  return v;
}

// ---------------------------------------------------------------- fp32 -> f16 convert
__global__ __launch_bounds__(256) void cvt_kernel(const float* __restrict__ src,
                                                  f16* __restrict__ dst, int n4) {
  int idx = blockIdx.x * blockDim.x + threadIdx.x;
  int stride = gridDim.x * blockDim.x;
  for (int i = idx; i < n4; i += stride) {
    float4 v = reinterpret_cast<const float4*>(src)[i];
    f16x4 h;
    h.x = (f16)v.x; h.y = (f16)v.y; h.z = (f16)v.z; h.w = (f16)v.w;
    reinterpret_cast<f16x4*>(dst)[i] = h;
  }
}

// ---------------------------------------------------------------- GEMM  C[M][N] = A[M][K] * B[N][K]^T
// 128x128 tile, BK=32, 4 waves (each a 64x64 quadrant), m97 structure + XCD swizzle.
// EPI==0: plain fp32 C.  EPI==1: fused RMS-norm (per 128-col head row) -> f16 Ch,
// with attention scale * log2e folded (Q path).
template <bool MB, int EPI>
__global__ __launch_bounds__(256, 2) void gemm_bt_f16(const f16* __restrict__ A,
                                                      const f16* __restrict__ Bw,
                                                      float* __restrict__ C,
                                                      f16* __restrict__ Ch,
                                                      const float* __restrict__ wvec,
                                                      int M, int N, int K) {
  __shared__ f16 As[2][128][32];
  __shared__ f16 Bs[2][128][32];
  const int tid = threadIdx.x;
  const int l = tid & 63, w = tid >> 6;
  const int lq = l & 15, lk = l >> 4;
  const int wr = w >> 1, wc = w & 1;
  // XCD-aware bijective swizzle (nwg % 8 == 0 for all our grids)
  const int nwg = gridDim.x * gridDim.y;
  const int p = blockIdx.y * gridDim.x + blockIdx.x;
  const int L = (p & 7) * (nwg >> 3) + (p >> 3);
  const int bx = L % gridDim.x, by = L / gridDim.x;
  const int brow = by * 128, bcol = bx * 128;
  const int srow = w * 16 + (l >> 2);   // staging row (+j*64)
  const int scol = (l & 3) * 8;         // staging col in f16 elems
  const int KT = K >> 5;

  f32x4 acc[4][4];
  f32x4 zf = {0.f, 0.f, 0.f, 0.f};
#pragma unroll
  for (int m = 0; m < 4; ++m)
#pragma unroll
    for (int n = 0; n < 4; ++n) acc[m][n] = zf;

  auto stage = [&](int kt, int buf) {
    const int k0 = kt * 32 + scol;
#pragma unroll
    for (int j = 0; j < 2; ++j) {
      int ra = brow + j * 64 + srow;
      if (MB) ra = (ra < M) ? ra : (M - 1);
      gload_lds16(A + (size_t)ra * K + k0,
                  (char*)(&As[buf][0][0]) + j * 4096 + w * 1024);
      int rb = bcol + j * 64 + srow;
      gload_lds16(Bw + (size_t)rb * K + k0,
                  (char*)(&Bs[buf][0][0]) + j * 4096 + w * 1024);
    }
  };

  stage(0, 0);
  for (int kt = 0; kt < KT; ++kt) {
    const int buf = kt & 1;
    __syncthreads();                 // drains vmcnt for stage(kt); also read/overwrite fence
    if (kt + 1 < KT) stage(kt + 1, buf ^ 1);  // prefetch overlaps this iter's compute
    f16x8 af[4], bf[4];
#pragma unroll
    for (int m = 0; m < 4; ++m)
      af[m] = *reinterpret_cast<const f16x8*>(&As[buf][wr * 64 + m * 16 + lq][lk * 8]);
#pragma unroll
    for (int n = 0; n < 4; ++n)
      bf[n] = *reinterpret_cast<const f16x8*>(&Bs[buf][wc * 64 + n * 16 + lq][lk * 8]);
#pragma unroll
    for (int m = 0; m < 4; ++m)
#pragma unroll
      for (int n = 0; n < 4; ++n)
        acc[m][n] = __builtin_amdgcn_mfma_f32_16x16x32_f16(af[m], bf[n], acc[m][n], 0, 0, 0);
  }

  if (EPI == 0) {
#pragma unroll
    for (int m = 0; m < 4; ++m) {
#pragma unroll
      for (int j = 0; j < 4; ++j) {
        int row = brow + wr * 64 + m * 16 + lk * 4 + j;
        if (MB && row >= M) continue;
        float* dst = C + (size_t)row * N + bcol + wc * 64 + lq;
#pragma unroll
        for (int n = 0; n < 4; ++n) dst[n * 16] = acc[m][n][j];
      }
    }
  } else {
    // fused RMS over the 128-col head row (block spans exactly one head)
    __syncthreads();                          // LDS reuse fence
    float* ssq = (float*)(&As[0][0][0]);      // [128][2] partial sums
#pragma unroll
    for (int m = 0; m < 4; ++m)
#pragma unroll
      for (int j = 0; j < 4; ++j) {
        int lr = wr * 64 + m * 16 + lk * 4 + j;
        float pp = 0.f;
#pragma unroll
        for (int n = 0; n < 4; ++n) pp += acc[m][n][j] * acc[m][n][j];
        pp += __shfl_xor(pp, 1);
        pp += __shfl_xor(pp, 2);
        pp += __shfl_xor(pp, 4);
        pp += __shfl_xor(pp, 8);
        if (lq == 0) ssq[lr * 2 + wc] = pp;
      }
    __syncthreads();
    float wv[4];
#pragma unroll
    for (int n = 0; n < 4; ++n) wv[n] = wvec[wc * 64 + n * 16 + lq];
#pragma unroll
    for (int m = 0; m < 4; ++m)
#pragma unroll
      for (int j = 0; j < 4; ++j) {
        int lr = wr * 64 + m * 16 + lk * 4 + j;
        float ss = ssq[lr * 2] + ssq[lr * 2 + 1];
        float rs = rsqrtf(ss * (1.0f / 128.0f) + 1e-5f) *
                   (0.08838834764831845f * 1.4426950408889634f);
        f16* dst = Ch + (size_t)(brow + lr) * N + bcol + wc * 64 + lq;
#pragma unroll
        for (int n = 0; n < 4; ++n) dst[n * 16] = (f16)(acc[m][n][j] * rs * wv[n]);
      }
  }
}

// ---------------------------------------------------------------- K RMS-norm + V transpose scatter
// KVraw [6404][2048] fp32 -> Kf [b][kvh][1664][128] f16 (normed), Vtf [b][kvh][128][1664] f16
__global__ __launch_bounds__(256) void kvscatter_kernel(const float* __restrict__ KVraw,
                                                        const float* __restrict__ wk,
                                                        f16* __restrict__ Kf,
                                                        f16* __restrict__ Vtf) {
  const int w = threadIdx.x >> 6, l = threadIdx.x & 63;
  const int gw = blockIdx.x * 4 + w;  // 0..51231
  const int r = gw >> 3, kvh = gw & 7;
  const int b = r / 1601, s = r - b * 1601;
  const float* kr = KVraw + (size_t)r * 2048 + kvh * 128;
  float2 kx = reinterpret_cast<const float2*>(kr)[l];
  float ss = wave_sum64(kx.x * kx.x + kx.y * kx.y);
  float rs = rsqrtf(ss * (1.0f / 128.0f) + 1e-5f);
  float2 wv = reinterpret_cast<const float2*>(wk)[l];
  union { f16 h[2]; unsigned u; } pk;
  pk.h[0] = (f16)(kx.x * rs * wv.x);
  pk.h[1] = (f16)(kx.y * rs * wv.y);
  reinterpret_cast<unsigned*>(Kf + ((size_t)(b * 8 + kvh) * 1664 + s) * 128)[l] = pk.u;
  const float* vr = kr + 1024;
  float2 vx = reinterpret_cast<const float2*>(vr)[l];
  f16* vcol = Vtf + ((size_t)(b * 8 + kvh) * 128 + l * 2) * 1664 + s;
  vcol[0] = (f16)vx.x;
  vcol[1664] = (f16)vx.y;
}

// ---------------------------------------------------------------- flash attention
// QBLK=128 as 8 waves x 16 q rows (512-thread block), KVBLK=64.
// LDS 80 KB: K dbuf 32K + V^T dbuf 32K + per-wave P 16K -> 2 blocks/CU = 16
// waves/CU (2x round-6's 8). Per-wave regs ~110 unified (o32+q16+s16) -> fits
// the 128-cap of 4 waves/SIMD under (512,4); r3/r5 spill signature watched.
// Sync structure identical to r6 (verified): counted vmcnt(4) keeps tile t+1's
// 4 staging issues in flight across the barrier; 2 barriers/tile.
__global__ __launch_bounds__(512, 4) void attn_kernel(const f16* __restrict__ Qf,
                                                      const f16* __restrict__ Kf,
                                                      const f16* __restrict__ Vtf,
                                                      f16* __restrict__ Oa) {
  __shared__ f16 Ksm[2][64][128];  // 32 KB dbuf, 256 B rows, XOR-swizzled
  __shared__ f16 Vsm[2][128][64];  // 32 KB dbuf, V^T [d][kv], 128 B rows, swizzled
  __shared__ f16 Psm[8][16][64];   // 16 KB per-wave P (wave-private)
  const int p = blockIdx.x;              // 0..1023
  const int L = (p & 7) * 128 + (p >> 3);
  const int qt = L & 7, h = (L >> 3) & 31, b = L >> 8;
  const int kvh = h >> 2;  // G = 4
  const int tid = threadIdx.x;
  const int l = tid & 63, w = tid >> 6;  // 8 waves
  const int lq = l & 15, lk = l >> 4;

  // Q fragments: wave w owns 16 q rows (qt*128 + w*16 ..)
  f16x8 qreg[4];
  const f16* Qbase = Qf + ((size_t)(b * 1024 + qt * 128 + w * 16)) * 4096 + h * 128;
#pragma unroll
  for (int ks = 0; ks < 4; ++ks)
    qreg[ks] = *reinterpret_cast<const f16x8*>(
        Qbase + (size_t)lq * 4096 + ks * 32 + lk * 8);

  const f16* Kb = Kf + (size_t)(b * 8 + kvh) * (1664 * 128);
  const f16* Vb = Vtf + (size_t)(b * 8 + kvh) * (128 * 1664);

  f32x4 o[8];
  f32x4 zf = {0.f, 0.f, 0.f, 0.f};
#pragma unroll
  for (int dn = 0; dn < 8; ++dn) o[dn] = zf;
  float mrow[4], lrow[4];  // per-lane partials (rows lk*4+j), reduced in epilogue
#pragma unroll
  for (int j = 0; j < 4; ++j) { mrow[j] = -1e30f; lrow[j] = 0.f; }

  char* Pw = (char*)(&Psm[w][0][0]);  // 16 rows x 128 B
  const int swzR = (lq & 7) << 4;

  auto stageK = [&](int t, int buf) {  // 16 KB over 8 waves: 2 issues/wave, 4 rows each
#pragma unroll
    for (int i = 0; i < 2; ++i) {
      int row = w * 8 + i * 4 + lk;
      int cb = (lq * 16) ^ ((row & 7) << 4);
      gload_lds16(Kb + (size_t)(t * 64 + row) * 128 + (cb >> 1),
                  (char*)(&Ksm[buf][0][0]) + w * 2048 + i * 1024);
    }
  };
  auto stageV = [&](int t, int buf) {  // 16 KB over 8 waves: 2 issues/wave, 8 rows each
#pragma unroll
    for (int i = 0; i < 2; ++i) {
      int r = w * 16 + i * 8 + (l >> 3);
      int cb = ((l & 7) * 16) ^ ((r & 7) << 4);
      gload_lds16(Vb + (size_t)r * 1664 + t * 64 + (cb >> 1),
                  (char*)(&Vsm[buf][0][0]) + w * 2048 + i * 1024);
    }
  };

  stageK(0, 0);
  stageV(0, 0);
  int cur = 0;
  for (int t = 0; t < 26; ++t) {
    if (t < 25) {
      stageK(t + 1, cur ^ 1);                       // 4 issues for tile t+1 in flight
      stageV(t + 1, cur ^ 1);
      asm volatile("s_waitcnt vmcnt(4)" ::: "memory");  // own tile-t loads done
    } else {
      asm volatile("s_waitcnt vmcnt(0)" ::: "memory");
    }
    __builtin_amdgcn_s_barrier();                   // all waves' tile-t loads done

    // ---- S = Q K^T (fp32 accum), wave's 16 q rows x 64 kv cols
    f32x4 s[4];
#pragma unroll
    for (int kn = 0; kn < 4; ++kn) s[kn] = zf;
    __builtin_amdgcn_s_setprio(1);
#pragma unroll
    for (int ks = 0; ks < 4; ++ks) {
      f16x8 bf[4];
#pragma unroll
      for (int kn = 0; kn < 4; ++kn)
        bf[kn] = *reinterpret_cast<const f16x8*>(
            (char*)(&Ksm[cur][0][0]) + (kn * 16 + lq) * 256 + ((ks * 64 + lk * 16) ^ swzR));
#pragma unroll
      for (int kn = 0; kn < 4; ++kn)
        s[kn] = __builtin_amdgcn_mfma_f32_16x16x32_f16(qreg[ks], bf[kn], s[kn], 0, 0, 0);
    }
    __builtin_amdgcn_s_setprio(0);

    // ---- mask tail (valid kv < 1601; tile 25 covers 1600..1663 -> local < 1)
    if (t == 25) {
#pragma unroll
      for (int kn = 0; kn < 4; ++kn) {
        bool valid = (kn * 16 + lq) < 1;
#pragma unroll
        for (int j = 0; j < 4; ++j) s[kn][j] = valid ? s[kn][j] : -1e30f;
      }
    }

    // ---- online softmax (log2 domain), defer-rescale THR=8, per-lane lrow partials
#pragma unroll
    for (int j = 0; j < 4; ++j) {
      float mt = fmaxf(fmaxf(s[0][j], s[1][j]), fmaxf(s[2][j], s[3][j]));
      mt = fmaxf(mt, __shfl_xor(mt, 1));
      mt = fmaxf(mt, __shfl_xor(mt, 2));
      mt = fmaxf(mt, __shfl_xor(mt, 4));
      mt = fmaxf(mt, __shfl_xor(mt, 8));
      float mo = mrow[j];
      if (mt > mo + 8.0f) {           // rarely taken after tile 0
        float corr = exp2f(mo - mt);
        mrow[j] = mt;
        lrow[j] *= corr;
#pragma unroll
        for (int dn = 0; dn < 8; ++dn) o[dn][j] *= corr;
        mo = mt;
      }
      float rsum = 0.f;
#pragma unroll
      for (int kn = 0; kn < 4; ++kn) {
        float pv = exp2f(s[kn][j] - mo);
        s[kn][j] = pv;
        rsum += pv;
      }
      lrow[j] += rsum;                // per-lane partial; no shfl here
      int prow = lk * 4 + j;
      int swzW = (prow & 7) << 4;
#pragma unroll
      for (int kn = 0; kn < 4; ++kn)
        *reinterpret_cast<f16*>(Pw + prow * 128 + (((kn * 16 + lq) * 2) ^ swzW)) =
            (f16)s[kn][j];
    }

    // ---- O += P V   (A = P from own Psm, B = V^T from Vsm[cur], both swizzled b128)
    __builtin_amdgcn_s_setprio(1);
#pragma unroll
    for (int c = 0; c < 2; ++c) {
      f16x8 pa = *reinterpret_cast<const f16x8*>(
          Pw + lq * 128 + ((c * 64 + lk * 16) ^ swzR));
      f16x8 vb[8];
#pragma unroll
      for (int dn = 0; dn < 8; ++dn)
        vb[dn] = *reinterpret_cast<const f16x8*>(
            (char*)(&Vsm[cur][0][0]) + (dn * 16 + lq) * 128 + ((c * 64 + lk * 16) ^ swzR));
#pragma unroll
      for (int dn = 0; dn < 8; ++dn)
        o[dn] = __builtin_amdgcn_mfma_f32_16x16x32_f16(pa, vb[dn], o[dn], 0, 0, 0);
    }
    __builtin_amdgcn_s_setprio(0);
    __builtin_amdgcn_s_barrier();   // all reads of buf `cur` done before next stage hits it
    cur ^= 1;
  }

  // ---- epilogue: reduce lrow partials across the 16-lane row group, then O/l
#pragma unroll
  for (int j = 0; j < 4; ++j) {
    float fl = lrow[j];
    fl += __shfl_xor(fl, 1);
    fl += __shfl_xor(fl, 2);
    fl += __shfl_xor(fl, 4);
    fl += __shfl_xor(fl, 8);
    float il = 1.0f / fl;
    int token = b * 1024 + qt * 128 + w * 16 + lk * 4 + j;
    f16* dst = Oa + (size_t)token * 4096 + h * 128;
#pragma unroll
    for (int dn = 0; dn < 8; ++dn) dst[dn * 16 + lq] = (f16)(o[dn][j] * il);
  }
}

// ---------------------------------------------------------------- launch
extern "C" void kernel_launch(void* const* d_in, const int* in_sizes, int n_in,
                              void* d_out, int out_size, void* d_ws, size_t ws_size,
                              hipStream_t stream) {
  const float* hidden = (const float*)d_in[0];  // [4,1024,4096]
  const float* cross  = (const float*)d_in[1];  // [4,1601,4096]
  const float* wqkv   = (const float*)d_in[2];  // [6144,4096]
  const float* wo     = (const float*)d_in[3];  // [4096,4096]
  const float* qw     = (const float*)d_in[4];  // [128]
  const float* kw     = (const float*)d_in[5];  // [128]

  char* ws = (char*)d_ws;
  // region A: hidden_f16 (33.55 MB) -> later attn_f16
  f16* hidden_h = (f16*)(ws + 0);
  f16* attn_h   = hidden_h;
  // region B: wqkv_f16 (50.33 MB)
  f16* wqkv_h = (f16*)(ws + 33554432);
  // region C: cross_f16 (52.46 MB) -> later K_f16 (13.63) + Vt_f16 (13.63)
  f16* cross_h = (f16*)(ws + 83886080);
  f16* k_h     = cross_h;
  f16* vt_h    = (f16*)(ws + 83886080 + 13631488);
  // region D: KVraw fp32 (52.46 MB) -> later wo_f16
  float* kvraw = (float*)(ws + 136347648);
  f16* wo_h    = (f16*)(ws + 136347648);
  // total ws use: 188,809,216 B
  // q_h lives in d_out (f16, 33.5 MB of the 67 MB fp32 buffer); it is fully
  // consumed by attn before the O-projection overwrites d_out.
  f16* q_h = (f16*)d_out;

  // 1) converts needed before projections
  cvt_kernel<<<2048, 256, 0, stream>>>(hidden, hidden_h, 16777216 / 4);
  cvt_kernel<<<2048, 256, 0, stream>>>(cross, cross_h, 26230784 / 4);
  cvt_kernel<<<2048, 256, 0, stream>>>(wqkv, wqkv_h, 25165824 / 4);
  // 2) KV projection: cross @ wqkv[4096:6144]^T -> KVraw [6404][2048]
  gemm_bt_f16<true, 0><<<dim3(16, 51), 256, 0, stream>>>(
      cross_h, wqkv_h + (size_t)4096 * 4096, kvraw, nullptr, nullptr, 6404, 2048, 4096);
  // 3) zero K/Vt pad cols (s in [1601,1664)), then scatter K (rms) + V (transpose)
  hipMemsetAsync(ws + 83886080, 0, 27262976, stream);
  kvscatter_kernel<<<12808, 256, 0, stream>>>(kvraw, kw, k_h, vt_h);
  // 4) wo convert (into dead KVraw region)
  cvt_kernel<<<2048, 256, 0, stream>>>(wo, wo_h, 16777216 / 4);
  // 5) Q projection with fused RMS-norm (+scale*log2e) -> f16 q_h (in d_out)
  gemm_bt_f16<false, 1><<<dim3(32, 32), 256, 0, stream>>>(
      hidden_h, wqkv_h, nullptr, q_h, qw, 4096, 4096, 4096);
  // 6) attention (8-wave blocks, grid 1024, XCD-swizzled in-kernel)
  attn_kernel<<<1024, 512, 0, stream>>>(q_h, k_h, vt_h, attn_h);
  // 7) output projection -> d_out
  gemm_bt_f16<false, 0><<<dim3(32, 32), 256, 0, stream>>>(
      attn_h, wo_h, (float*)d_out, nullptr, nullptr, 4096, 4096, 4096);
}

// Round 9
// 685.072 us; speedup vs baseline: 1.6698x; 1.2123x over previous
//
#include <hip/hip_runtime.h>
#include <cstdint>
#include <math.h>

typedef _Float16 f16;
typedef __attribute__((ext_vector_type(4))) _Float16 f16x4;
typedef __attribute__((ext_vector_type(8))) _Float16 f16x8;
typedef __attribute__((ext_vector_type(4))) float f32x4;

// ---------------------------------------------------------------- helpers
__device__ inline void gload_lds16(const void* g, void* l) {
  auto gp = reinterpret_cast<const __attribute__((address_space(1))) uint32_t*>(
      reinterpret_cast<uintptr_t>(g));
  auto lp = reinterpret_cast<__attribute__((address_space(3))) uint32_t*>(
      reinterpret_cast<uintptr_t>(l));
  __builtin_amdgcn_global_load_lds(gp, lp, 16 /*bytes*/, 0, 0);
}

__device__ inline float wave_sum64(float v) {
#pragma unroll
  for (int m = 1; m < 64; m <<= 1) v += __shfl_xor(v, m);
  return v;
}

// ---------------------------------------------------------------- fp32 -> f16 convert
__global__ __launch_bounds__(256) void cvt_kernel(const float* __restrict__ src,
                                                  f16* __restrict__ dst, int n4) {
  int idx = blockIdx.x * blockDim.x + threadIdx.x;
  int stride = gridDim.x * blockDim.x;
  for (int i = idx; i < n4; i += stride) {
    float4 v = reinterpret_cast<const float4*>(src)[i];
    f16x4 h;
    h.x = (f16)v.x; h.y = (f16)v.y; h.z = (f16)v.z; h.w = (f16)v.w;
    reinterpret_cast<f16x4*>(dst)[i] = h;
  }
}

// ---------------------------------------------------------------- 256x256 8-phase GEMM
// C[M][N] = A[M][K] * B[N][K]^T.  512 thr / 8 waves (2M x 4N), per-wave 128x64,
// BK=64, LDS 128 KB (A,B dbuf [256][64] f16, st-swizzled), 1 block/CU, 256-VGPR class.
// Per K-tile: 4 quadrant-phases, 2 gload_lds issues/phase, counted vmcnt(2) at
// phase 0 only (prefetch never drained), 2 raw barriers/phase, setprio around MFMA.
// Swizzle (rule #21, both sides): LDS byte col c' = c ^ ((row&7)<<4); staging
// pre-swizzles the GLOBAL source col; ds_read XORs the same pattern.
// EPI==0: fp32 C.  EPI==1: fused per-128-col RMS-norm -> f16 Ch (Q path, scale*log2e).
template <bool MB, int EPI>
__global__ __launch_bounds__(512, 2) void gemm256(const f16* __restrict__ A,
                                                  const f16* __restrict__ Bw,
                                                  float* __restrict__ C,
                                                  f16* __restrict__ Ch,
                                                  const float* __restrict__ wvec,
                                                  int M, int N, int K) {
  __shared__ f16 As[2][256][64];
  __shared__ f16 Bs[2][256][64];
  const int tid = threadIdx.x;
  const int l = tid & 63, w = tid >> 6;  // 8 waves
  const int lq = l & 15, lk = l >> 4;
  const int wm = w >> 2, wn = w & 3;     // 2M x 4N wave grid
  // XCD-aware bijective swizzle (nwg % 8 == 0 for all grids used)
  const int nwg = gridDim.x * gridDim.y;
  const int p = blockIdx.y * gridDim.x + blockIdx.x;
  const int L = (p & 7) * (nwg >> 3) + (p >> 3);
  const int bx = L % gridDim.x, by = L / gridDim.x;
  const int brow = by * 256, bcol = bx * 256;
  const int KT = K >> 6;

  // staging constants: issue i covers rows i*64..i*64+63 (8 rows/wave, 8 lanes/row)
  const int srow8 = w * 8 + (l >> 3);            // + i*64
  const int scol  = ((l & 7) ^ (l >> 3)) * 8;    // f16 elems, pre-swizzled source col
  const int swz   = (lq & 7) << 4;               // read-side XOR (row&7 == lq&7)

  f32x4 acc[8][4];
  f32x4 zf = {0.f, 0.f, 0.f, 0.f};
#pragma unroll
  for (int m = 0; m < 8; ++m)
#pragma unroll
    for (int n = 0; n < 4; ++n) acc[m][n] = zf;

  auto stageA = [&](int kt, int buf, int i) {
    int ra = brow + i * 64 + srow8;
    if (MB) ra = (ra < M) ? ra : (M - 1);
    gload_lds16(A + (size_t)ra * K + kt * 64 + scol,
                (char*)(&As[buf][0][0]) + i * 8192 + w * 1024);
  };
  auto stageB = [&](int kt, int buf, int i) {
    int rb = bcol + i * 64 + srow8;
    gload_lds16(Bw + (size_t)rb * K + kt * 64 + scol,
                (char*)(&Bs[buf][0][0]) + i * 8192 + w * 1024);
  };
  auto ldA = [&](int buf, int m, int kk) -> f16x8 {
    int r = wm * 128 + m * 16 + lq;
    return *reinterpret_cast<const f16x8*>(
        (char*)(&As[buf][0][0]) + r * 128 + ((kk * 64 + lk * 16) ^ swz));
  };
  auto ldB = [&](int buf, int n, int kk) -> f16x8 {
    int r = wn * 64 + n * 16 + lq;
    return *reinterpret_cast<const f16x8*>(
        (char*)(&Bs[buf][0][0]) + r * 128 + ((kk * 64 + lk * 16) ^ swz));
  };

  // prologue: stage tile 0 (8 issues, matching in-loop issue order A0..3,B0..3)
#pragma unroll
  for (int i = 0; i < 4; ++i) stageA(0, 0, i);
#pragma unroll
  for (int i = 0; i < 4; ++i) stageB(0, 0, i);

  f16x8 av[4][2], bv[2][2];
  for (int t = 0; t < KT; ++t) {
    const int buf = t & 1, nbuf = buf ^ 1;
    const bool pf = (t + 1 < KT);

    // ---- phase 0: quadrant (m 0-3, n 0-1)
    if (pf) { stageA(t + 1, nbuf, 0); stageA(t + 1, nbuf, 1); }
    if (pf) asm volatile("s_waitcnt vmcnt(2)" ::: "memory");
    else    asm volatile("s_waitcnt vmcnt(0)" ::: "memory");
    __builtin_amdgcn_s_barrier();
#pragma unroll
    for (int mm = 0; mm < 4; ++mm)
#pragma unroll
      for (int kk = 0; kk < 2; ++kk) av[mm][kk] = ldA(buf, mm, kk);
#pragma unroll
    for (int nn = 0; nn < 2; ++nn)
#pragma unroll
      for (int kk = 0; kk < 2; ++kk) bv[nn][kk] = ldB(buf, nn, kk);
    __builtin_amdgcn_s_setprio(1);
#pragma unroll
    for (int mm = 0; mm < 4; ++mm)
#pragma unroll
      for (int nn = 0; nn < 2; ++nn)
#pragma unroll
        for (int kk = 0; kk < 2; ++kk)
          acc[mm][nn] = __builtin_amdgcn_mfma_f32_16x16x32_f16(av[mm][kk], bv[nn][kk], acc[mm][nn], 0, 0, 0);
    __builtin_amdgcn_s_setprio(0);
    asm volatile("" ::: "memory");
    __builtin_amdgcn_s_barrier();

    // ---- phase 1: quadrant (m 4-7, n 0-1), reuse bv
#pragma unroll
    for (int mm = 0; mm < 4; ++mm)
#pragma unroll
      for (int kk = 0; kk < 2; ++kk) av[mm][kk] = ldA(buf, 4 + mm, kk);
    if (pf) { stageA(t + 1, nbuf, 2); stageA(t + 1, nbuf, 3); }
    asm volatile("" ::: "memory");
    __builtin_amdgcn_s_barrier();
    __builtin_amdgcn_s_setprio(1);
#pragma unroll
    for (int mm = 0; mm < 4; ++mm)
#pragma unroll
      for (int nn = 0; nn < 2; ++nn)
#pragma unroll
        for (int kk = 0; kk < 2; ++kk)
          acc[4 + mm][nn] = __builtin_amdgcn_mfma_f32_16x16x32_f16(av[mm][kk], bv[nn][kk], acc[4 + mm][nn], 0, 0, 0);
    __builtin_amdgcn_s_setprio(0);
    asm volatile("" ::: "memory");
    __builtin_amdgcn_s_barrier();

    // ---- phase 2: quadrant (m 4-7, n 2-3), reuse av
#pragma unroll
    for (int nn = 0; nn < 2; ++nn)
#pragma unroll
      for (int kk = 0; kk < 2; ++kk) bv[nn][kk] = ldB(buf, 2 + nn, kk);
    if (pf) { stageB(t + 1, nbuf, 0); stageB(t + 1, nbuf, 1); }
    asm volatile("" ::: "memory");
    __builtin_amdgcn_s_barrier();
    __builtin_amdgcn_s_setprio(1);
#pragma unroll
    for (int mm = 0; mm < 4; ++mm)
#pragma unroll
      for (int nn = 0; nn < 2; ++nn)
#pragma unroll
        for (int kk = 0; kk < 2; ++kk)
          acc[4 + mm][2 + nn] = __builtin_amdgcn_mfma_f32_16x16x32_f16(av[mm][kk], bv[nn][kk], acc[4 + mm][2 + nn], 0, 0, 0);
    __builtin_amdgcn_s_setprio(0);
    asm volatile("" ::: "memory");
    __builtin_amdgcn_s_barrier();

    // ---- phase 3: quadrant (m 0-3, n 2-3), reuse bv, re-read A m0-3
#pragma unroll
    for (int mm = 0; mm < 4; ++mm)
#pragma unroll
      for (int kk = 0; kk < 2; ++kk) av[mm][kk] = ldA(buf, mm, kk);
    if (pf) { stageB(t + 1, nbuf, 2); stageB(t + 1, nbuf, 3); }
    asm volatile("" ::: "memory");
    __builtin_amdgcn_s_barrier();
    __builtin_amdgcn_s_setprio(1);
#pragma unroll
    for (int mm = 0; mm < 4; ++mm)
#pragma unroll
      for (int nn = 0; nn < 2; ++nn)
#pragma unroll
        for (int kk = 0; kk < 2; ++kk)
          acc[mm][2 + nn] = __builtin_amdgcn_mfma_f32_16x16x32_f16(av[mm][kk], bv[nn][kk], acc[mm][2 + nn], 0, 0, 0);
    __builtin_amdgcn_s_setprio(0);
    asm volatile("" ::: "memory");
    __builtin_amdgcn_s_barrier();   // end of tile: all reads of buf done
  }

  if (EPI == 0) {
#pragma unroll
    for (int m = 0; m < 8; ++m) {
#pragma unroll
      for (int j = 0; j < 4; ++j) {
        int row = brow + wm * 128 + m * 16 + lk * 4 + j;
        if (MB && row >= M) continue;
        float* dst = C + (size_t)row * N + bcol + wn * 64 + lq;
#pragma unroll
        for (int n = 0; n < 4; ++n) dst[n * 16] = acc[m][n][j];
      }
    }
  } else {
    // fused RMS over each 128-col head group (tile spans 2 heads; wn pairs per head)
    __shared__ float ssq[256][4];
#pragma unroll
    for (int m = 0; m < 8; ++m)
#pragma unroll
      for (int j = 0; j < 4; ++j) {
        int lr = wm * 128 + m * 16 + lk * 4 + j;
        float pp = 0.f;
#pragma unroll
        for (int n = 0; n < 4; ++n) pp += acc[m][n][j] * acc[m][n][j];
        pp += __shfl_xor(pp, 1);
        pp += __shfl_xor(pp, 2);
        pp += __shfl_xor(pp, 4);
        pp += __shfl_xor(pp, 8);
        if (lq == 0) ssq[lr][wn] = pp;
      }
    asm volatile("" ::: "memory");
    __builtin_amdgcn_s_barrier();
    const int hh = wn >> 1;  // head within tile
    float wv[4];
#pragma unroll
    for (int n = 0; n < 4; ++n) wv[n] = wvec[(wn * 64 + n * 16 + lq) & 127];
#pragma unroll
    for (int m = 0; m < 8; ++m)
#pragma unroll
      for (int j = 0; j < 4; ++j) {
        int lr = wm * 128 + m * 16 + lk * 4 + j;
        float ss = ssq[lr][hh * 2] + ssq[lr][hh * 2 + 1];
        float rs = rsqrtf(ss * (1.0f / 128.0f) + 1e-5f) *
                   (0.08838834764831845f * 1.4426950408889634f);
        f16* dst = Ch + (size_t)(brow + lr) * N + bcol + wn * 64 + lq;
#pragma unroll
        for (int n = 0; n < 4; ++n) dst[n * 16] = (f16)(acc[m][n][j] * rs * wv[n]);
      }
  }
}

// ---------------------------------------------------------------- K RMS-norm + V transpose scatter
// KVraw [6404][2048] fp32 -> Kf [b][kvh][1664][128] f16 (normed), Vtf [b][kvh][128][1664] f16
__global__ __launch_bounds__(256) void kvscatter_kernel(const float* __restrict__ KVraw,
                                                        const float* __restrict__ wk,
                                                        f16* __restrict__ Kf,
                                                        f16* __restrict__ Vtf) {
  const int w = threadIdx.x >> 6, l = threadIdx.x & 63;
  const int gw = blockIdx.x * 4 + w;  // 0..51231
  const int r = gw >> 3, kvh = gw & 7;
  const int b = r / 1601, s = r - b * 1601;
  const float* kr = KVraw + (size_t)r * 2048 + kvh * 128;
  float2 kx = reinterpret_cast<const float2*>(kr)[l];
  float ss = wave_sum64(kx.x * kx.x + kx.y * kx.y);
  float rs = rsqrtf(ss * (1.0f / 128.0f) + 1e-5f);
  float2 wv = reinterpret_cast<const float2*>(wk)[l];
  union { f16 h[2]; unsigned u; } pk;
  pk.h[0] = (f16)(kx.x * rs * wv.x);
  pk.h[1] = (f16)(kx.y * rs * wv.y);
  reinterpret_cast<unsigned*>(Kf + ((size_t)(b * 8 + kvh) * 1664 + s) * 128)[l] = pk.u;
  const float* vr = kr + 1024;
  float2 vx = reinterpret_cast<const float2*>(vr)[l];
  f16* vcol = Vtf + ((size_t)(b * 8 + kvh) * 128 + l * 2) * 1664 + s;
  vcol[0] = (f16)vx.x;
  vcol[1664] = (f16)vx.y;
}

// ---------------------------------------------------------------- flash attention (r8 state, 213 us)
// QBLK=128 as 8 waves x 16 q rows (512-thread block), KVBLK=64.  LDS 80 KB.
__global__ __launch_bounds__(512, 4) void attn_kernel(const f16* __restrict__ Qf,
                                                      const f16* __restrict__ Kf,
                                                      const f16* __restrict__ Vtf,
                                                      f16* __restrict__ Oa) {
  __shared__ f16 Ksm[2][64][128];  // 32 KB dbuf, 256 B rows, XOR-swizzled
  __shared__ f16 Vsm[2][128][64];  // 32 KB dbuf, V^T [d][kv], 128 B rows, swizzled
  __shared__ f16 Psm[8][16][64];   // 16 KB per-wave P (wave-private)
  const int p = blockIdx.x;              // 0..1023
  const int L = (p & 7) * 128 + (p >> 3);
  const int qt = L & 7, h = (L >> 3) & 31, b = L >> 8;
  const int kvh = h >> 2;  // G = 4
  const int tid = threadIdx.x;
  const int l = tid & 63, w = tid >> 6;  // 8 waves
  const int lq = l & 15, lk = l >> 4;

  f16x8 qreg[4];
  const f16* Qbase = Qf + ((size_t)(b * 1024 + qt * 128 + w * 16)) * 4096 + h * 128;
#pragma unroll
  for (int ks = 0; ks < 4; ++ks)
    qreg[ks] = *reinterpret_cast<const f16x8*>(
        Qbase + (size_t)lq * 4096 + ks * 32 + lk * 8);

  const f16* Kb = Kf + (size_t)(b * 8 + kvh) * (1664 * 128);
  const f16* Vb = Vtf + (size_t)(b * 8 + kvh) * (128 * 1664);

  f32x4 o[8];
  f32x4 zf = {0.f, 0.f, 0.f, 0.f};
#pragma unroll
  for (int dn = 0; dn < 8; ++dn) o[dn] = zf;
  float mrow[4], lrow[4];
#pragma unroll
  for (int j = 0; j < 4; ++j) { mrow[j] = -1e30f; lrow[j] = 0.f; }

  char* Pw = (char*)(&Psm[w][0][0]);
  const int swzR = (lq & 7) << 4;

  auto stageK = [&](int t, int buf) {
#pragma unroll
    for (int i = 0; i < 2; ++i) {
      int row = w * 8 + i * 4 + lk;
      int cb = (lq * 16) ^ ((row & 7) << 4);
      gload_lds16(Kb + (size_t)(t * 64 + row) * 128 + (cb >> 1),
                  (char*)(&Ksm[buf][0][0]) + w * 2048 + i * 1024);
    }
  };
  auto stageV = [&](int t, int buf) {
#pragma unroll
    for (int i = 0; i < 2; ++i) {
      int r = w * 16 + i * 8 + (l >> 3);
      int cb = ((l & 7) * 16) ^ ((r & 7) << 4);
      gload_lds16(Vb + (size_t)r * 1664 + t * 64 + (cb >> 1),
                  (char*)(&Vsm[buf][0][0]) + w * 2048 + i * 1024);
    }
  };

  stageK(0, 0);
  stageV(0, 0);
  int cur = 0;
  for (int t = 0; t < 26; ++t) {
    if (t < 25) {
      stageK(t + 1, cur ^ 1);
      stageV(t + 1, cur ^ 1);
      asm volatile("s_waitcnt vmcnt(4)" ::: "memory");
    } else {
      asm volatile("s_waitcnt vmcnt(0)" ::: "memory");
    }
    __builtin_amdgcn_s_barrier();

    f32x4 s[4];
#pragma unroll
    for (int kn = 0; kn < 4; ++kn) s[kn] = zf;
    __builtin_amdgcn_s_setprio(1);
#pragma unroll
    for (int ks = 0; ks < 4; ++ks) {
      f16x8 bf[4];
#pragma unroll
      for (int kn = 0; kn < 4; ++kn)
        bf[kn] = *reinterpret_cast<const f16x8*>(
            (char*)(&Ksm[cur][0][0]) + (kn * 16 + lq) * 256 + ((ks * 64 + lk * 16) ^ swzR));
#pragma unroll
      for (int kn = 0; kn < 4; ++kn)
        s[kn] = __builtin_amdgcn_mfma_f32_16x16x32_f16(qreg[ks], bf[kn], s[kn], 0, 0, 0);
    }
    __builtin_amdgcn_s_setprio(0);

    if (t == 25) {
#pragma unroll
      for (int kn = 0; kn < 4; ++kn) {
        bool valid = (kn * 16 + lq) < 1;
#pragma unroll
        for (int j = 0; j < 4; ++j) s[kn][j] = valid ? s[kn][j] : -1e30f;
      }
    }

#pragma unroll
    for (int j = 0; j < 4; ++j) {
      float mt = fmaxf(fmaxf(s[0][j], s[1][j]), fmaxf(s[2][j], s[3][j]));
      mt = fmaxf(mt, __shfl_xor(mt, 1));
      mt = fmaxf(mt, __shfl_xor(mt, 2));
      mt = fmaxf(mt, __shfl_xor(mt, 4));
      mt = fmaxf(mt, __shfl_xor(mt, 8));
      float mo = mrow[j];
      if (mt > mo + 8.0f) {
        float corr = exp2f(mo - mt);
        mrow[j] = mt;
        lrow[j] *= corr;
#pragma unroll
        for (int dn = 0; dn < 8; ++dn) o[dn][j] *= corr;
        mo = mt;
      }
      float rsum = 0.f;
#pragma unroll
      for (int kn = 0; kn < 4; ++kn) {
        float pv = exp2f(s[kn][j] - mo);
        s[kn][j] = pv;
        rsum += pv;
      }
      lrow[j] += rsum;
      int prow = lk * 4 + j;
      int swzW = (prow & 7) << 4;
#pragma unroll
      for (int kn = 0; kn < 4; ++kn)
        *reinterpret_cast<f16*>(Pw + prow * 128 + (((kn * 16 + lq) * 2) ^ swzW)) =
            (f16)s[kn][j];
    }

    __builtin_amdgcn_s_setprio(1);
#pragma unroll
    for (int c = 0; c < 2; ++c) {
      f16x8 pa = *reinterpret_cast<const f16x8*>(
          Pw + lq * 128 + ((c * 64 + lk * 16) ^ swzR));
      f16x8 vb[8];
#pragma unroll
      for (int dn = 0; dn < 8; ++dn)
        vb[dn] = *reinterpret_cast<const f16x8*>(
            (char*)(&Vsm[cur][0][0]) + (dn * 16 + lq) * 128 + ((c * 64 + lk * 16) ^ swzR));
#pragma unroll
      for (int dn = 0; dn < 8; ++dn)
        o[dn] = __builtin_amdgcn_mfma_f32_16x16x32_f16(pa, vb[dn], o[dn], 0, 0, 0);
    }
    __builtin_amdgcn_s_setprio(0);
    __builtin_amdgcn_s_barrier();
    cur ^= 1;
  }

#pragma unroll
  for (int j = 0; j < 4; ++j) {
    float fl = lrow[j];
    fl += __shfl_xor(fl, 1);
    fl += __shfl_xor(fl, 2);
    fl += __shfl_xor(fl, 4);
    fl += __shfl_xor(fl, 8);
    float il = 1.0f / fl;
    int token = b * 1024 + qt * 128 + w * 16 + lk * 4 + j;
    f16* dst = Oa + (size_t)token * 4096 + h * 128;
#pragma unroll
    for (int dn = 0; dn < 8; ++dn) dst[dn * 16 + lq] = (f16)(o[dn][j] * il);
  }
}

// ---------------------------------------------------------------- launch
extern "C" void kernel_launch(void* const* d_in, const int* in_sizes, int n_in,
                              void* d_out, int out_size, void* d_ws, size_t ws_size,
                              hipStream_t stream) {
  const float* hidden = (const float*)d_in[0];  // [4,1024,4096]
  const float* cross  = (const float*)d_in[1];  // [4,1601,4096]
  const float* wqkv   = (const float*)d_in[2];  // [6144,4096]
  const float* wo     = (const float*)d_in[3];  // [4096,4096]
  const float* qw     = (const float*)d_in[4];  // [128]
  const float* kw     = (const float*)d_in[5];  // [128]

  char* ws = (char*)d_ws;
  f16* hidden_h = (f16*)(ws + 0);            // 33.55 MB -> later attn_h
  f16* attn_h   = hidden_h;
  f16* wqkv_h = (f16*)(ws + 33554432);       // 50.33 MB
  f16* cross_h = (f16*)(ws + 83886080);      // 52.46 MB -> later K + Vt
  f16* k_h     = cross_h;
  f16* vt_h    = (f16*)(ws + 83886080 + 13631488);
  float* kvraw = (float*)(ws + 136347648);   // 52.46 MB -> later wo_h
  f16* wo_h    = (f16*)(ws + 136347648);
  f16* q_h = (f16*)d_out;  // consumed by attn before O-proj overwrites d_out

  // 1) converts
  cvt_kernel<<<2048, 256, 0, stream>>>(hidden, hidden_h, 16777216 / 4);
  cvt_kernel<<<2048, 256, 0, stream>>>(cross, cross_h, 26230784 / 4);
  cvt_kernel<<<2048, 256, 0, stream>>>(wqkv, wqkv_h, 25165824 / 4);
  // 2) KV projection: cross @ wqkv[4096:6144]^T -> KVraw [6404][2048]
  gemm256<true, 0><<<dim3(8, 26), 512, 0, stream>>>(
      cross_h, wqkv_h + (size_t)4096 * 4096, kvraw, nullptr, nullptr, 6404, 2048, 4096);
  // 3) zero K/Vt pads, scatter K (rms) + V (transpose)
  hipMemsetAsync(ws + 83886080, 0, 27262976, stream);
  kvscatter_kernel<<<12808, 256, 0, stream>>>(kvraw, kw, k_h, vt_h);
  // 4) wo convert (into dead KVraw region)
  cvt_kernel<<<2048, 256, 0, stream>>>(wo, wo_h, 16777216 / 4);
  // 5) Q projection with fused RMS-norm (+scale*log2e) -> f16 q_h (in d_out)
  gemm256<false, 1><<<dim3(16, 16), 512, 0, stream>>>(
      hidden_h, wqkv_h, nullptr, q_h, qw, 4096, 4096, 4096);
  // 6) attention
  attn_kernel<<<1024, 512, 0, stream>>>(q_h, k_h, vt_h, attn_h);
  // 7) output projection -> d_out
  gemm256<false, 0><<<dim3(16, 16), 512, 0, stream>>>(
      attn_h, wo_h, (float*)d_out, nullptr, nullptr, 4096, 4096, 4096);
}

// Round 10
// 671.008 us; speedup vs baseline: 1.7048x; 1.0210x over previous
//
#include <hip/hip_runtime.h>
#include <cstdint>
#include <math.h>

typedef _Float16 f16;
typedef __attribute__((ext_vector_type(4))) _Float16 f16x4;
typedef __attribute__((ext_vector_type(8))) _Float16 f16x8;
typedef __attribute__((ext_vector_type(4))) float f32x4;

// ---------------------------------------------------------------- helpers
__device__ inline void gload_lds16(const void* g, void* l) {
  auto gp = reinterpret_cast<const __attribute__((address_space(1))) uint32_t*>(
      reinterpret_cast<uintptr_t>(g));
  auto lp = reinterpret_cast<__attribute__((address_space(3))) uint32_t*>(
      reinterpret_cast<uintptr_t>(l));
  __builtin_amdgcn_global_load_lds(gp, lp, 16 /*bytes*/, 0, 0);
}

// ---------------------------------------------------------------- fused fp32->f16 converts + zero-fill
// R0 hidden (4194304 f4) R1 cross (6557696) R2 wqkv (6291456) R3 zero K/Vt (1703936 x16B)
__global__ __launch_bounds__(256) void cvtzero_kernel(const float* __restrict__ s0, f16* __restrict__ d0,
                                                      const float* __restrict__ s1, f16* __restrict__ d1,
                                                      const float* __restrict__ s2, f16* __restrict__ d2,
                                                      float4* __restrict__ z) {
  int idx = blockIdx.x * blockDim.x + threadIdx.x;
  int stride = gridDim.x * blockDim.x;
  for (int i = idx; i < 18747392; i += stride) {
    const float* src; f16* dst; int k;
    if (i < 4194304) { src = s0; dst = d0; k = i; }
    else if (i < 10752000) { src = s1; dst = d1; k = i - 4194304; }
    else if (i < 17043456) { src = s2; dst = d2; k = i - 10752000; }
    else { float4 zr = {0.f, 0.f, 0.f, 0.f}; z[i - 17043456] = zr; continue; }
    float4 v = reinterpret_cast<const float4*>(src)[k];
    f16x4 h;
    h.x = (f16)v.x; h.y = (f16)v.y; h.z = (f16)v.z; h.w = (f16)v.w;
    reinterpret_cast<f16x4*>(dst)[k] = h;
  }
}

// ---------------------------------------------------------------- plain fp32 -> f16 convert (wo)
__global__ __launch_bounds__(256) void cvt_kernel(const float* __restrict__ src,
                                                  f16* __restrict__ dst, int n4) {
  int idx = blockIdx.x * blockDim.x + threadIdx.x;
  int stride = gridDim.x * blockDim.x;
  for (int i = idx; i < n4; i += stride) {
    float4 v = reinterpret_cast<const float4*>(src)[i];
    f16x4 h;
    h.x = (f16)v.x; h.y = (f16)v.y; h.z = (f16)v.z; h.w = (f16)v.w;
    reinterpret_cast<f16x4*>(dst)[i] = h;
  }
}

// ---------------------------------------------------------------- 256x256 8-phase GEMM
// C[M][N] = A[M][K] * B[N][K]^T.  512 thr / 8 waves (2M x 4N), per-wave 128x64,
// BK=64, LDS 128 KB dbuf, counted vmcnt(2), 2 raw barriers/phase, setprio.
// EPI==0: fp32 C.
// EPI==1: fused per-128-col RMS-norm -> f16 Ch (Q path, scale*log2e folded).
// EPI==2: KV path. K-half tiles (bcol<1024): RMS(wvec) -> Kf[b][kvh][s][d].
//         V-half tiles: transpose scatter -> Vtf[b][kvh][d][s].  (s = r mod 1601)
template <bool MB, int EPI>
__global__ __launch_bounds__(512, 2) void gemm256(const f16* __restrict__ A,
                                                  const f16* __restrict__ Bw,
                                                  float* __restrict__ C,
                                                  f16* __restrict__ Ch,
                                                  const float* __restrict__ wvec,
                                                  f16* __restrict__ Vtf,
                                                  int M, int N, int K) {
  __shared__ f16 As[2][256][64];
  __shared__ f16 Bs[2][256][64];
  const int tid = threadIdx.x;
  const int l = tid & 63, w = tid >> 6;  // 8 waves
  const int lq = l & 15, lk = l >> 4;
  const int wm = w >> 2, wn = w & 3;     // 2M x 4N wave grid
  // XCD-aware bijective swizzle (nwg % 8 == 0 for all grids used)
  const int nwg = gridDim.x * gridDim.y;
  const int p = blockIdx.y * gridDim.x + blockIdx.x;
  const int L = (p & 7) * (nwg >> 3) + (p >> 3);
  const int bx = L % gridDim.x, by = L / gridDim.x;
  const int brow = by * 256, bcol = bx * 256;
  const int KT = K >> 6;

  const int srow8 = w * 8 + (l >> 3);            // + i*64
  const int scol  = ((l & 7) ^ (l >> 3)) * 8;    // pre-swizzled source col (f16)
  const int swz   = (lq & 7) << 4;               // read-side XOR

  f32x4 acc[8][4];
  f32x4 zf = {0.f, 0.f, 0.f, 0.f};
#pragma unroll
  for (int m = 0; m < 8; ++m)
#pragma unroll
    for (int n = 0; n < 4; ++n) acc[m][n] = zf;

  auto stageA = [&](int kt, int buf, int i) {
    int ra = brow + i * 64 + srow8;
    if (MB) ra = (ra < M) ? ra : (M - 1);
    gload_lds16(A + (size_t)ra * K + kt * 64 + scol,
                (char*)(&As[buf][0][0]) + i * 8192 + w * 1024);
  };
  auto stageB = [&](int kt, int buf, int i) {
    int rb = bcol + i * 64 + srow8;
    gload_lds16(Bw + (size_t)rb * K + kt * 64 + scol,
                (char*)(&Bs[buf][0][0]) + i * 8192 + w * 1024);
  };
  auto ldA = [&](int buf, int m, int kk) -> f16x8 {
    int r = wm * 128 + m * 16 + lq;
    return *reinterpret_cast<const f16x8*>(
        (char*)(&As[buf][0][0]) + r * 128 + ((kk * 64 + lk * 16) ^ swz));
  };
  auto ldB = [&](int buf, int n, int kk) -> f16x8 {
    int r = wn * 64 + n * 16 + lq;
    return *reinterpret_cast<const f16x8*>(
        (char*)(&Bs[buf][0][0]) + r * 128 + ((kk * 64 + lk * 16) ^ swz));
  };

#pragma unroll
  for (int i = 0; i < 4; ++i) stageA(0, 0, i);
#pragma unroll
  for (int i = 0; i < 4; ++i) stageB(0, 0, i);

  f16x8 av[4][2], bv[2][2];
  for (int t = 0; t < KT; ++t) {
    const int buf = t & 1, nbuf = buf ^ 1;
    const bool pf = (t + 1 < KT);

    // ---- phase 0: quadrant (m 0-3, n 0-1)
    if (pf) { stageA(t + 1, nbuf, 0); stageA(t + 1, nbuf, 1); }
    if (pf) asm volatile("s_waitcnt vmcnt(2)" ::: "memory");
    else    asm volatile("s_waitcnt vmcnt(0)" ::: "memory");
    __builtin_amdgcn_s_barrier();
#pragma unroll
    for (int mm = 0; mm < 4; ++mm)
#pragma unroll
      for (int kk = 0; kk < 2; ++kk) av[mm][kk] = ldA(buf, mm, kk);
#pragma unroll
    for (int nn = 0; nn < 2; ++nn)
#pragma unroll
      for (int kk = 0; kk < 2; ++kk) bv[nn][kk] = ldB(buf, nn, kk);
    __builtin_amdgcn_s_setprio(1);
#pragma unroll
    for (int mm = 0; mm < 4; ++mm)
#pragma unroll
      for (int nn = 0; nn < 2; ++nn)
#pragma unroll
        for (int kk = 0; kk < 2; ++kk)
          acc[mm][nn] = __builtin_amdgcn_mfma_f32_16x16x32_f16(av[mm][kk], bv[nn][kk], acc[mm][nn], 0, 0, 0);
    __builtin_amdgcn_s_setprio(0);
    asm volatile("" ::: "memory");
    __builtin_amdgcn_s_barrier();

    // ---- phase 1: quadrant (m 4-7, n 0-1), reuse bv
#pragma unroll
    for (int mm = 0; mm < 4; ++mm)
#pragma unroll
      for (int kk = 0; kk < 2; ++kk) av[mm][kk] = ldA(buf, 4 + mm, kk);
    if (pf) { stageA(t + 1, nbuf, 2); stageA(t + 1, nbuf, 3); }
    asm volatile("" ::: "memory");
    __builtin_amdgcn_s_barrier();
    __builtin_amdgcn_s_setprio(1);
#pragma unroll
    for (int mm = 0; mm < 4; ++mm)
#pragma unroll
      for (int nn = 0; nn < 2; ++nn)
#pragma unroll
        for (int kk = 0; kk < 2; ++kk)
          acc[4 + mm][nn] = __builtin_amdgcn_mfma_f32_16x16x32_f16(av[mm][kk], bv[nn][kk], acc[4 + mm][nn], 0, 0, 0);
    __builtin_amdgcn_s_setprio(0);
    asm volatile("" ::: "memory");
    __builtin_amdgcn_s_barrier();

    // ---- phase 2: quadrant (m 4-7, n 2-3), reuse av
#pragma unroll
    for (int nn = 0; nn < 2; ++nn)
#pragma unroll
      for (int kk = 0; kk < 2; ++kk) bv[nn][kk] = ldB(buf, 2 + nn, kk);
    if (pf) { stageB(t + 1, nbuf, 0); stageB(t + 1, nbuf, 1); }
    asm volatile("" ::: "memory");
    __builtin_amdgcn_s_barrier();
    __builtin_amdgcn_s_setprio(1);
#pragma unroll
    for (int mm = 0; mm < 4; ++mm)
#pragma unroll
      for (int nn = 0; nn < 2; ++nn)
#pragma unroll
        for (int kk = 0; kk < 2; ++kk)
          acc[4 + mm][2 + nn] = __builtin_amdgcn_mfma_f32_16x16x32_f16(av[mm][kk], bv[nn][kk], acc[4 + mm][2 + nn], 0, 0, 0);
    __builtin_amdgcn_s_setprio(0);
    asm volatile("" ::: "memory");
    __builtin_amdgcn_s_barrier();

    // ---- phase 3: quadrant (m 0-3, n 2-3), reuse bv, re-read A m0-3
#pragma unroll
    for (int mm = 0; mm < 4; ++mm)
#pragma unroll
      for (int kk = 0; kk < 2; ++kk) av[mm][kk] = ldA(buf, mm, kk);
    if (pf) { stageB(t + 1, nbuf, 2); stageB(t + 1, nbuf, 3); }
    asm volatile("" ::: "memory");
    __builtin_amdgcn_s_barrier();
    __builtin_amdgcn_s_setprio(1);
#pragma unroll
    for (int mm = 0; mm < 4; ++mm)
#pragma unroll
      for (int nn = 0; nn < 2; ++nn)
#pragma unroll
        for (int kk = 0; kk < 2; ++kk)
          acc[mm][2 + nn] = __builtin_amdgcn_mfma_f32_16x16x32_f16(av[mm][kk], bv[nn][kk], acc[mm][2 + nn], 0, 0, 0);
    __builtin_amdgcn_s_setprio(0);
    asm volatile("" ::: "memory");
    __builtin_amdgcn_s_barrier();
  }

  if (EPI == 0) {
#pragma unroll
    for (int m = 0; m < 8; ++m) {
#pragma unroll
      for (int j = 0; j < 4; ++j) {
        int row = brow + wm * 128 + m * 16 + lk * 4 + j;
        if (MB && row >= M) continue;
        float* dst = C + (size_t)row * N + bcol + wn * 64 + lq;
#pragma unroll
        for (int n = 0; n < 4; ++n) dst[n * 16] = acc[m][n][j];
      }
    }
  } else if (EPI == 1) {
    // fused RMS over each 128-col head group (tile spans 2 heads)
    __shared__ float ssq[256][4];
#pragma unroll
    for (int m = 0; m < 8; ++m)
#pragma unroll
      for (int j = 0; j < 4; ++j) {
        int lr = wm * 128 + m * 16 + lk * 4 + j;
        float pp = 0.f;
#pragma unroll
        for (int n = 0; n < 4; ++n) pp += acc[m][n][j] * acc[m][n][j];
        pp += __shfl_xor(pp, 1);
        pp += __shfl_xor(pp, 2);
        pp += __shfl_xor(pp, 4);
        pp += __shfl_xor(pp, 8);
        if (lq == 0) ssq[lr][wn] = pp;
      }
    asm volatile("" ::: "memory");
    __builtin_amdgcn_s_barrier();
    const int hh = wn >> 1;
    float wv[4];
#pragma unroll
    for (int n = 0; n < 4; ++n) wv[n] = wvec[(wn * 64 + n * 16 + lq) & 127];
#pragma unroll
    for (int m = 0; m < 8; ++m)
#pragma unroll
      for (int j = 0; j < 4; ++j) {
        int lr = wm * 128 + m * 16 + lk * 4 + j;
        float ss = ssq[lr][hh * 2] + ssq[lr][hh * 2 + 1];
        float rs = rsqrtf(ss * (1.0f / 128.0f) + 1e-5f) *
                   (0.08838834764831845f * 1.4426950408889634f);
        f16* dst = Ch + (size_t)(brow + lr) * N + bcol + wn * 64 + lq;
#pragma unroll
        for (int n = 0; n < 4; ++n) dst[n * 16] = (f16)(acc[m][n][j] * rs * wv[n]);
      }
  } else {
    // EPI==2: KV path.  rows r = b*1601+s (M=6404); K half: RMS -> Kf; V half -> Vtf^T
    const bool isK = (bcol < 1024);
    __shared__ float ssq[256][4];
    if (isK) {
#pragma unroll
      for (int m = 0; m < 8; ++m)
#pragma unroll
        for (int j = 0; j < 4; ++j) {
          int lr = wm * 128 + m * 16 + lk * 4 + j;
          float pp = 0.f;
#pragma unroll
          for (int n = 0; n < 4; ++n) pp += acc[m][n][j] * acc[m][n][j];
          pp += __shfl_xor(pp, 1);
          pp += __shfl_xor(pp, 2);
          pp += __shfl_xor(pp, 4);
          pp += __shfl_xor(pp, 8);
          if (lq == 0) ssq[lr][wn] = pp;
        }
      asm volatile("" ::: "memory");
      __builtin_amdgcn_s_barrier();
    }
    const int hh = wn >> 1;
    float wv[4];
    if (isK) {
#pragma unroll
      for (int n = 0; n < 4; ++n) wv[n] = wvec[(wn * 64 + n * 16 + lq) & 127];
    }
#pragma unroll
    for (int m = 0; m < 8; ++m) {
#pragma unroll
      for (int j = 0; j < 4; ++j) {
        int lr = wm * 128 + m * 16 + lk * 4 + j;
        int r = brow + lr;
        if (r >= M) continue;
        unsigned bb = (unsigned)r / 1601u;
        unsigned s = (unsigned)r - bb * 1601u;
        if (isK) {
          float ss = ssq[lr][hh * 2] + ssq[lr][hh * 2 + 1];
          float rs = rsqrtf(ss * (1.0f / 128.0f) + 1e-5f);
#pragma unroll
          for (int n = 0; n < 4; ++n) {
            int col = wn * 64 + n * 16 + lq;
            int kvh = (bcol + col) >> 7;
            int d = col & 127;
            Ch[((size_t)(bb * 8 + kvh) * 1664 + s) * 128 + d] =
                (f16)(acc[m][n][j] * rs * wv[n]);
          }
        } else {
#pragma unroll
          for (int n = 0; n < 4; ++n) {
            int col = bcol - 1024 + wn * 64 + n * 16 + lq;
            int kvh = col >> 7;
            int d = col & 127;
            Vtf[((size_t)(bb * 8 + kvh) * 128 + d) * 1664 + s] = (f16)acc[m][n][j];
          }
        }
      }
    }
  }
}

// ---------------------------------------------------------------- flash attention (r8 state, 213 us)
// QBLK=128 as 8 waves x 16 q rows (512-thread block), KVBLK=64.  LDS 80 KB.
__global__ __launch_bounds__(512, 4) void attn_kernel(const f16* __restrict__ Qf,
                                                      const f16* __restrict__ Kf,
                                                      const f16* __restrict__ Vtf,
                                                      f16* __restrict__ Oa) {
  __shared__ f16 Ksm[2][64][128];  // 32 KB dbuf, 256 B rows, XOR-swizzled
  __shared__ f16 Vsm[2][128][64];  // 32 KB dbuf, V^T [d][kv], 128 B rows, swizzled
  __shared__ f16 Psm[8][16][64];   // 16 KB per-wave P (wave-private)
  const int p = blockIdx.x;              // 0..1023
  const int L = (p & 7) * 128 + (p >> 3);
  const int qt = L & 7, h = (L >> 3) & 31, b = L >> 8;
  const int kvh = h >> 2;  // G = 4
  const int tid = threadIdx.x;
  const int l = tid & 63, w = tid >> 6;  // 8 waves
  const int lq = l & 15, lk = l >> 4;

  f16x8 qreg[4];
  const f16* Qbase = Qf + ((size_t)(b * 1024 + qt * 128 + w * 16)) * 4096 + h * 128;
#pragma unroll
  for (int ks = 0; ks < 4; ++ks)
    qreg[ks] = *reinterpret_cast<const f16x8*>(
        Qbase + (size_t)lq * 4096 + ks * 32 + lk * 8);

  const f16* Kb = Kf + (size_t)(b * 8 + kvh) * (1664 * 128);
  const f16* Vb = Vtf + (size_t)(b * 8 + kvh) * (128 * 1664);

  f32x4 o[8];
  f32x4 zf = {0.f, 0.f, 0.f, 0.f};
#pragma unroll
  for (int dn = 0; dn < 8; ++dn) o[dn] = zf;
  float mrow[4], lrow[4];
#pragma unroll
  for (int j = 0; j < 4; ++j) { mrow[j] = -1e30f; lrow[j] = 0.f; }

  char* Pw = (char*)(&Psm[w][0][0]);
  const int swzR = (lq & 7) << 4;

  auto stageK = [&](int t, int buf) {
#pragma unroll
    for (int i = 0; i < 2; ++i) {
      int row = w * 8 + i * 4 + lk;
      int cb = (lq * 16) ^ ((row & 7) << 4);
      gload_lds16(Kb + (size_t)(t * 64 + row) * 128 + (cb >> 1),
                  (char*)(&Ksm[buf][0][0]) + w * 2048 + i * 1024);
    }
  };
  auto stageV = [&](int t, int buf) {
#pragma unroll
    for (int i = 0; i < 2; ++i) {
      int r = w * 16 + i * 8 + (l >> 3);
      int cb = ((l & 7) * 16) ^ ((r & 7) << 4);
      gload_lds16(Vb + (size_t)r * 1664 + t * 64 + (cb >> 1),
                  (char*)(&Vsm[buf][0][0]) + w * 2048 + i * 1024);
    }
  };

  stageK(0, 0);
  stageV(0, 0);
  int cur = 0;
  for (int t = 0; t < 26; ++t) {
    if (t < 25) {
      stageK(t + 1, cur ^ 1);
      stageV(t + 1, cur ^ 1);
      asm volatile("s_waitcnt vmcnt(4)" ::: "memory");
    } else {
      asm volatile("s_waitcnt vmcnt(0)" ::: "memory");
    }
    __builtin_amdgcn_s_barrier();

    f32x4 s[4];
#pragma unroll
    for (int kn = 0; kn < 4; ++kn) s[kn] = zf;
    __builtin_amdgcn_s_setprio(1);
#pragma unroll
    for (int ks = 0; ks < 4; ++ks) {
      f16x8 bf[4];
#pragma unroll
      for (int kn = 0; kn < 4; ++kn)
        bf[kn] = *reinterpret_cast<const f16x8*>(
            (char*)(&Ksm[cur][0][0]) + (kn * 16 + lq) * 256 + ((ks * 64 + lk * 16) ^ swzR));
#pragma unroll
      for (int kn = 0; kn < 4; ++kn)
        s[kn] = __builtin_amdgcn_mfma_f32_16x16x32_f16(qreg[ks], bf[kn], s[kn], 0, 0, 0);
    }
    __builtin_amdgcn_s_setprio(0);

    if (t == 25) {
#pragma unroll
      for (int kn = 0; kn < 4; ++kn) {
        bool valid = (kn * 16 + lq) < 1;
#pragma unroll
        for (int j = 0; j < 4; ++j) s[kn][j] = valid ? s[kn][j] : -1e30f;
      }
    }

#pragma unroll
    for (int j = 0; j < 4; ++j) {
      float mt = fmaxf(fmaxf(s[0][j], s[1][j]), fmaxf(s[2][j], s[3][j]));
      mt = fmaxf(mt, __shfl_xor(mt, 1));
      mt = fmaxf(mt, __shfl_xor(mt, 2));
      mt = fmaxf(mt, __shfl_xor(mt, 4));
      mt = fmaxf(mt, __shfl_xor(mt, 8));
      float mo = mrow[j];
      if (mt > mo + 8.0f) {
        float corr = exp2f(mo - mt);
        mrow[j] = mt;
        lrow[j] *= corr;
#pragma unroll
        for (int dn = 0; dn < 8; ++dn) o[dn][j] *= corr;
        mo = mt;
      }
      float rsum = 0.f;
#pragma unroll
      for (int kn = 0; kn < 4; ++kn) {
        float pv = exp2f(s[kn][j] - mo);
        s[kn][j] = pv;
        rsum += pv;
      }
      lrow[j] += rsum;
      int prow = lk * 4 + j;
      int swzW = (prow & 7) << 4;
#pragma unroll
      for (int kn = 0; kn < 4; ++kn)
        *reinterpret_cast<f16*>(Pw + prow * 128 + (((kn * 16 + lq) * 2) ^ swzW)) =
            (f16)s[kn][j];
    }

    __builtin_amdgcn_s_setprio(1);
#pragma unroll
    for (int c = 0; c < 2; ++c) {
      f16x8 pa = *reinterpret_cast<const f16x8*>(
          Pw + lq * 128 + ((c * 64 + lk * 16) ^ swzR));
      f16x8 vb[8];
#pragma unroll
      for (int dn = 0; dn < 8; ++dn)
        vb[dn] = *reinterpret_cast<const f16x8*>(
            (char*)(&Vsm[cur][0][0]) + (dn * 16 + lq) * 128 + ((c * 64 + lk * 16) ^ swzR));
#pragma unroll
      for (int dn = 0; dn < 8; ++dn)
        o[dn] = __builtin_amdgcn_mfma_f32_16x16x32_f16(pa, vb[dn], o[dn], 0, 0, 0);
    }
    __builtin_amdgcn_s_setprio(0);
    __builtin_amdgcn_s_barrier();
    cur ^= 1;
  }

#pragma unroll
  for (int j = 0; j < 4; ++j) {
    float fl = lrow[j];
    fl += __shfl_xor(fl, 1);
    fl += __shfl_xor(fl, 2);
    fl += __shfl_xor(fl, 4);
    fl += __shfl_xor(fl, 8);
    float il = 1.0f / fl;
    int token = b * 1024 + qt * 128 + w * 16 + lk * 4 + j;
    f16* dst = Oa + (size_t)token * 4096 + h * 128;
#pragma unroll
    for (int dn = 0; dn < 8; ++dn) dst[dn * 16 + lq] = (f16)(o[dn][j] * il);
  }
}

// ---------------------------------------------------------------- launch
extern "C" void kernel_launch(void* const* d_in, const int* in_sizes, int n_in,
                              void* d_out, int out_size, void* d_ws, size_t ws_size,
                              hipStream_t stream) {
  const float* hidden = (const float*)d_in[0];  // [4,1024,4096]
  const float* cross  = (const float*)d_in[1];  // [4,1601,4096]
  const float* wqkv   = (const float*)d_in[2];  // [6144,4096]
  const float* wo     = (const float*)d_in[3];  // [4096,4096]
  const float* qw     = (const float*)d_in[4];  // [128]
  const float* kw     = (const float*)d_in[5];  // [128]

  char* ws = (char*)d_ws;
  // region A @0:          hidden_h (33.55 MB) -> attn_h after Q-proj consumes it
  f16* hidden_h = (f16*)(ws + 0);
  f16* attn_h   = hidden_h;
  // region B @33554432:   wqkv_h (50.33 MB), live through Q-proj
  f16* wqkv_h = (f16*)(ws + 33554432);
  // region C @83886080:   cross_h (52.46 MB) -> wo_h after KV-proj consumes it
  f16* cross_h = (f16*)(ws + 83886080);
  f16* wo_h    = (f16*)(ws + 83886080);
  // region D @136347648:  k_h (13.63 MB) + vt_h (13.63 MB)  (no kvraw anymore;
  //                       distinct from region C because KV-proj reads C while
  //                       its epilogue writes D)
  f16* k_h  = (f16*)(ws + 136347648);
  f16* vt_h = (f16*)(ws + 136347648 + 13631488);
  // total ws use: 163,610,624 B (< r9's 188.8 MB)
  f16* q_h = (f16*)d_out;  // consumed by attn before O-proj overwrites d_out

  // 1) fused converts (hidden, cross, wqkv) + zero-fill of K/Vt pads
  cvtzero_kernel<<<2048, 256, 0, stream>>>(hidden, hidden_h, cross, cross_h,
                                           wqkv, wqkv_h, (float4*)(ws + 136347648));
  // 2) KV projection with fused K-RMS + V-transpose epilogue
  gemm256<true, 2><<<dim3(8, 26), 512, 0, stream>>>(
      cross_h, wqkv_h + (size_t)4096 * 4096, nullptr, k_h, kw, vt_h, 6404, 2048, 4096);
  // 3) wo convert (into dead cross_h region)
  cvt_kernel<<<2048, 256, 0, stream>>>(wo, wo_h, 16777216 / 4);
  // 4) Q projection with fused RMS-norm (+scale*log2e) -> f16 q_h (in d_out)
  gemm256<false, 1><<<dim3(16, 16), 512, 0, stream>>>(
      hidden_h, wqkv_h, nullptr, q_h, qw, nullptr, 4096, 4096, 4096);
  // 5) attention
  attn_kernel<<<1024, 512, 0, stream>>>(q_h, k_h, vt_h, attn_h);
  // 6) output projection -> d_out
  gemm256<false, 0><<<dim3(16, 16), 512, 0, stream>>>(
      attn_h, wo_h, (float*)d_out, nullptr, nullptr, nullptr, 4096, 4096, 4096);
}

// Round 11
// 633.861 us; speedup vs baseline: 1.8047x; 1.0586x over previous
//
#include <hip/hip_runtime.h>
#include <cstdint>
#include <math.h>

typedef _Float16 f16;
typedef __attribute__((ext_vector_type(4))) _Float16 f16x4;
typedef __attribute__((ext_vector_type(8))) _Float16 f16x8;
typedef __attribute__((ext_vector_type(4))) float f32x4;

// ---------------------------------------------------------------- helpers
__device__ inline void gload_lds16(const void* g, void* l) {
  auto gp = reinterpret_cast<const __attribute__((address_space(1))) uint32_t*>(
      reinterpret_cast<uintptr_t>(g));
  auto lp = reinterpret_cast<__attribute__((address_space(3))) uint32_t*>(
      reinterpret_cast<uintptr_t>(l));
  __builtin_amdgcn_global_load_lds(gp, lp, 16 /*bytes*/, 0, 0);
}

// ---------------------------------------------------------------- fused fp32->f16 converts + zero-fill
// R0 hidden (4194304 f4) R1 cross (6557696) R2 wqkv (6291456) R3 zero K/Vt (1703936 x16B)
__global__ __launch_bounds__(256) void cvtzero_kernel(const float* __restrict__ s0, f16* __restrict__ d0,
                                                      const float* __restrict__ s1, f16* __restrict__ d1,
                                                      const float* __restrict__ s2, f16* __restrict__ d2,
                                                      float4* __restrict__ z) {
  int idx = blockIdx.x * blockDim.x + threadIdx.x;
  int stride = gridDim.x * blockDim.x;
  for (int i = idx; i < 18747392; i += stride) {
    const float* src; f16* dst; int k;
    if (i < 4194304) { src = s0; dst = d0; k = i; }
    else if (i < 10752000) { src = s1; dst = d1; k = i - 4194304; }
    else if (i < 17043456) { src = s2; dst = d2; k = i - 10752000; }
    else { float4 zr = {0.f, 0.f, 0.f, 0.f}; z[i - 17043456] = zr; continue; }
    float4 v = reinterpret_cast<const float4*>(src)[k];
    f16x4 h;
    h.x = (f16)v.x; h.y = (f16)v.y; h.z = (f16)v.z; h.w = (f16)v.w;
    reinterpret_cast<f16x4*>(dst)[k] = h;
  }
}

// ---------------------------------------------------------------- plain fp32 -> f16 convert (wo)
__global__ __launch_bounds__(256) void cvt_kernel(const float* __restrict__ src,
                                                  f16* __restrict__ dst, int n4) {
  int idx = blockIdx.x * blockDim.x + threadIdx.x;
  int stride = gridDim.x * blockDim.x;
  for (int i = idx; i < n4; i += stride) {
    float4 v = reinterpret_cast<const float4*>(src)[i];
    f16x4 h;
    h.x = (f16)v.x; h.y = (f16)v.y; h.z = (f16)v.z; h.w = (f16)v.w;
    reinterpret_cast<f16x4*>(dst)[i] = h;
  }
}

// ---------------------------------------------------------------- 256x256 8-phase GEMM
// C[M][N] = A[M][K] * B[N][K]^T.  512 thr / 8 waves (2M x 4N), per-wave 128x64,
// BK=64, LDS 128 KB dbuf, counted vmcnt(2), 2 raw barriers/phase, setprio.
// EPI==0: fp32 C.
// EPI==1: fused per-128-col RMS-norm -> f16 Ch (Q path, scale*log2e folded).
// EPI==2: KV path. K-half tiles (bcol<1024): RMS(wvec) -> Kf[b][kvh][s][d].
//         V-half tiles: transpose scatter -> Vtf[b][kvh][d][s].  (s = r mod 1601)
template <bool MB, int EPI>
__global__ __launch_bounds__(512, 2) void gemm256(const f16* __restrict__ A,
                                                  const f16* __restrict__ Bw,
                                                  float* __restrict__ C,
                                                  f16* __restrict__ Ch,
                                                  const float* __restrict__ wvec,
                                                  f16* __restrict__ Vtf,
                                                  int M, int N, int K) {
  __shared__ f16 As[2][256][64];
  __shared__ f16 Bs[2][256][64];
  const int tid = threadIdx.x;
  const int l = tid & 63, w = tid >> 6;  // 8 waves
  const int lq = l & 15, lk = l >> 4;
  const int wm = w >> 2, wn = w & 3;     // 2M x 4N wave grid
  // XCD-aware bijective swizzle (nwg % 8 == 0 for all grids used)
  const int nwg = gridDim.x * gridDim.y;
  const int p = blockIdx.y * gridDim.x + blockIdx.x;
  const int L = (p & 7) * (nwg >> 3) + (p >> 3);
  const int bx = L % gridDim.x, by = L / gridDim.x;
  const int brow = by * 256, bcol = bx * 256;
  const int KT = K >> 6;

  const int srow8 = w * 8 + (l >> 3);            // + i*64
  const int scol  = ((l & 7) ^ (l >> 3)) * 8;    // pre-swizzled source col (f16)
  const int swz   = (lq & 7) << 4;               // read-side XOR

  f32x4 acc[8][4];
  f32x4 zf = {0.f, 0.f, 0.f, 0.f};
#pragma unroll
  for (int m = 0; m < 8; ++m)
#pragma unroll
    for (int n = 0; n < 4; ++n) acc[m][n] = zf;

  auto stageA = [&](int kt, int buf, int i) {
    int ra = brow + i * 64 + srow8;
    if (MB) ra = (ra < M) ? ra : (M - 1);
    gload_lds16(A + (size_t)ra * K + kt * 64 + scol,
                (char*)(&As[buf][0][0]) + i * 8192 + w * 1024);
  };
  auto stageB = [&](int kt, int buf, int i) {
    int rb = bcol + i * 64 + srow8;
    gload_lds16(Bw + (size_t)rb * K + kt * 64 + scol,
                (char*)(&Bs[buf][0][0]) + i * 8192 + w * 1024);
  };
  auto ldA = [&](int buf, int m, int kk) -> f16x8 {
    int r = wm * 128 + m * 16 + lq;
    return *reinterpret_cast<const f16x8*>(
        (char*)(&As[buf][0][0]) + r * 128 + ((kk * 64 + lk * 16) ^ swz));
  };
  auto ldB = [&](int buf, int n, int kk) -> f16x8 {
    int r = wn * 64 + n * 16 + lq;
    return *reinterpret_cast<const f16x8*>(
        (char*)(&Bs[buf][0][0]) + r * 128 + ((kk * 64 + lk * 16) ^ swz));
  };

#pragma unroll
  for (int i = 0; i < 4; ++i) stageA(0, 0, i);
#pragma unroll
  for (int i = 0; i < 4; ++i) stageB(0, 0, i);

  f16x8 av[4][2], bv[2][2];
  for (int t = 0; t < KT; ++t) {
    const int buf = t & 1, nbuf = buf ^ 1;
    const bool pf = (t + 1 < KT);

    // ---- phase 0: quadrant (m 0-3, n 0-1)
    if (pf) { stageA(t + 1, nbuf, 0); stageA(t + 1, nbuf, 1); }
    if (pf) asm volatile("s_waitcnt vmcnt(2)" ::: "memory");
    else    asm volatile("s_waitcnt vmcnt(0)" ::: "memory");
    __builtin_amdgcn_s_barrier();
#pragma unroll
    for (int mm = 0; mm < 4; ++mm)
#pragma unroll
      for (int kk = 0; kk < 2; ++kk) av[mm][kk] = ldA(buf, mm, kk);
#pragma unroll
    for (int nn = 0; nn < 2; ++nn)
#pragma unroll
      for (int kk = 0; kk < 2; ++kk) bv[nn][kk] = ldB(buf, nn, kk);
    __builtin_amdgcn_s_setprio(1);
#pragma unroll
    for (int mm = 0; mm < 4; ++mm)
#pragma unroll
      for (int nn = 0; nn < 2; ++nn)
#pragma unroll
        for (int kk = 0; kk < 2; ++kk)
          acc[mm][nn] = __builtin_amdgcn_mfma_f32_16x16x32_f16(av[mm][kk], bv[nn][kk], acc[mm][nn], 0, 0, 0);
    __builtin_amdgcn_s_setprio(0);
    asm volatile("" ::: "memory");
    __builtin_amdgcn_s_barrier();

    // ---- phase 1: quadrant (m 4-7, n 0-1), reuse bv
#pragma unroll
    for (int mm = 0; mm < 4; ++mm)
#pragma unroll
      for (int kk = 0; kk < 2; ++kk) av[mm][kk] = ldA(buf, 4 + mm, kk);
    if (pf) { stageA(t + 1, nbuf, 2); stageA(t + 1, nbuf, 3); }
    asm volatile("" ::: "memory");
    __builtin_amdgcn_s_barrier();
    __builtin_amdgcn_s_setprio(1);
#pragma unroll
    for (int mm = 0; mm < 4; ++mm)
#pragma unroll
      for (int nn = 0; nn < 2; ++nn)
#pragma unroll
        for (int kk = 0; kk < 2; ++kk)
          acc[4 + mm][nn] = __builtin_amdgcn_mfma_f32_16x16x32_f16(av[mm][kk], bv[nn][kk], acc[4 + mm][nn], 0, 0, 0);
    __builtin_amdgcn_s_setprio(0);
    asm volatile("" ::: "memory");
    __builtin_amdgcn_s_barrier();

    // ---- phase 2: quadrant (m 4-7, n 2-3), reuse av
#pragma unroll
    for (int nn = 0; nn < 2; ++nn)
#pragma unroll
      for (int kk = 0; kk < 2; ++kk) bv[nn][kk] = ldB(buf, 2 + nn, kk);
    if (pf) { stageB(t + 1, nbuf, 0); stageB(t + 1, nbuf, 1); }
    asm volatile("" ::: "memory");
    __builtin_amdgcn_s_barrier();
    __builtin_amdgcn_s_setprio(1);
#pragma unroll
    for (int mm = 0; mm < 4; ++mm)
#pragma unroll
      for (int nn = 0; nn < 2; ++nn)
#pragma unroll
        for (int kk = 0; kk < 2; ++kk)
          acc[4 + mm][2 + nn] = __builtin_amdgcn_mfma_f32_16x16x32_f16(av[mm][kk], bv[nn][kk], acc[4 + mm][2 + nn], 0, 0, 0);
    __builtin_amdgcn_s_setprio(0);
    asm volatile("" ::: "memory");
    __builtin_amdgcn_s_barrier();

    // ---- phase 3: quadrant (m 0-3, n 2-3), reuse bv, re-read A m0-3
#pragma unroll
    for (int mm = 0; mm < 4; ++mm)
#pragma unroll
      for (int kk = 0; kk < 2; ++kk) av[mm][kk] = ldA(buf, mm, kk);
    if (pf) { stageB(t + 1, nbuf, 2); stageB(t + 1, nbuf, 3); }
    asm volatile("" ::: "memory");
    __builtin_amdgcn_s_barrier();
    __builtin_amdgcn_s_setprio(1);
#pragma unroll
    for (int mm = 0; mm < 4; ++mm)
#pragma unroll
      for (int nn = 0; nn < 2; ++nn)
#pragma unroll
        for (int kk = 0; kk < 2; ++kk)
          acc[mm][2 + nn] = __builtin_amdgcn_mfma_f32_16x16x32_f16(av[mm][kk], bv[nn][kk], acc[mm][2 + nn], 0, 0, 0);
    __builtin_amdgcn_s_setprio(0);
    asm volatile("" ::: "memory");
    __builtin_amdgcn_s_barrier();
  }

  if (EPI == 0) {
#pragma unroll
    for (int m = 0; m < 8; ++m) {
#pragma unroll
      for (int j = 0; j < 4; ++j) {
        int row = brow + wm * 128 + m * 16 + lk * 4 + j;
        if (MB && row >= M) continue;
        float* dst = C + (size_t)row * N + bcol + wn * 64 + lq;
#pragma unroll
        for (int n = 0; n < 4; ++n) dst[n * 16] = acc[m][n][j];
      }
    }
  } else if (EPI == 1) {
    // fused RMS over each 128-col head group (tile spans 2 heads)
    __shared__ float ssq[256][4];
#pragma unroll
    for (int m = 0; m < 8; ++m)
#pragma unroll
      for (int j = 0; j < 4; ++j) {
        int lr = wm * 128 + m * 16 + lk * 4 + j;
        float pp = 0.f;
#pragma unroll
        for (int n = 0; n < 4; ++n) pp += acc[m][n][j] * acc[m][n][j];
        pp += __shfl_xor(pp, 1);
        pp += __shfl_xor(pp, 2);
        pp += __shfl_xor(pp, 4);
        pp += __shfl_xor(pp, 8);
        if (lq == 0) ssq[lr][wn] = pp;
      }
    asm volatile("" ::: "memory");
    __builtin_amdgcn_s_barrier();
    const int hh = wn >> 1;
    float wv[4];
#pragma unroll
    for (int n = 0; n < 4; ++n) wv[n] = wvec[(wn * 64 + n * 16 + lq) & 127];
#pragma unroll
    for (int m = 0; m < 8; ++m)
#pragma unroll
      for (int j = 0; j < 4; ++j) {
        int lr = wm * 128 + m * 16 + lk * 4 + j;
        float ss = ssq[lr][hh * 2] + ssq[lr][hh * 2 + 1];
        float rs = rsqrtf(ss * (1.0f / 128.0f) + 1e-5f) *
                   (0.08838834764831845f * 1.4426950408889634f);
        f16* dst = Ch + (size_t)(brow + lr) * N + bcol + wn * 64 + lq;
#pragma unroll
        for (int n = 0; n < 4; ++n) dst[n * 16] = (f16)(acc[m][n][j] * rs * wv[n]);
      }
  } else {
    // EPI==2: KV path.  rows r = b*1601+s (M=6404); K half: RMS -> Kf; V half -> Vtf^T
    const bool isK = (bcol < 1024);
    __shared__ float ssq[256][4];
    if (isK) {
#pragma unroll
      for (int m = 0; m < 8; ++m)
#pragma unroll
        for (int j = 0; j < 4; ++j) {
          int lr = wm * 128 + m * 16 + lk * 4 + j;
          float pp = 0.f;
#pragma unroll
          for (int n = 0; n < 4; ++n) pp += acc[m][n][j] * acc[m][n][j];
          pp += __shfl_xor(pp, 1);
          pp += __shfl_xor(pp, 2);
          pp += __shfl_xor(pp, 4);
          pp += __shfl_xor(pp, 8);
          if (lq == 0) ssq[lr][wn] = pp;
        }
      asm volatile("" ::: "memory");
      __builtin_amdgcn_s_barrier();
    }
    const int hh = wn >> 1;
    float wv[4];
    if (isK) {
#pragma unroll
      for (int n = 0; n < 4; ++n) wv[n] = wvec[(wn * 64 + n * 16 + lq) & 127];
    }
#pragma unroll
    for (int m = 0; m < 8; ++m) {
#pragma unroll
      for (int j = 0; j < 4; ++j) {
        int lr = wm * 128 + m * 16 + lk * 4 + j;
        int r = brow + lr;
        if (r >= M) continue;
        unsigned bb = (unsigned)r / 1601u;
        unsigned s = (unsigned)r - bb * 1601u;
        if (isK) {
          float ss = ssq[lr][hh * 2] + ssq[lr][hh * 2 + 1];
          float rs = rsqrtf(ss * (1.0f / 128.0f) + 1e-5f);
#pragma unroll
          for (int n = 0; n < 4; ++n) {
            int col = wn * 64 + n * 16 + lq;
            int kvh = (bcol + col) >> 7;
            int d = col & 127;
            Ch[((size_t)(bb * 8 + kvh) * 1664 + s) * 128 + d] =
                (f16)(acc[m][n][j] * rs * wv[n]);
          }
        } else {
#pragma unroll
          for (int n = 0; n < 4; ++n) {
            int col = bcol - 1024 + wn * 64 + n * 16 + lq;
            int kvh = col >> 7;
            int d = col & 127;
            Vtf[((size_t)(bb * 8 + kvh) * 128 + d) * 1664 + s] = (f16)acc[m][n][j];
          }
        }
      }
    }
  }
}

// ---------------------------------------------------------------- flash attention
// QBLK=128 as 8 waves x 16 q rows (512-thread block), KVBLK=64.  LDS 80 KB.
// STATIC-MAX softmax: Q is RMS-normed * (HD^-0.5 * log2e), K is RMS-normed, so
// the log2-domain logit is bounded: |s| <= 128*0.0884*1.443 = 16.33.  With
// static max M=8: P = 2^(s-8) <= 2^8.33 = 322 << f16 max; typical row max ~+5
// -> P_max ~ 2^-3, entries in full f16 normal range.  No max tracking, no
// rescale, no shfl in the tile loop.  The -8 is folded into the MFMA C-init.
__global__ __launch_bounds__(512, 4) void attn_kernel(const f16* __restrict__ Qf,
                                                      const f16* __restrict__ Kf,
                                                      const f16* __restrict__ Vtf,
                                                      f16* __restrict__ Oa) {
  __shared__ f16 Ksm[2][64][128];  // 32 KB dbuf, 256 B rows, XOR-swizzled
  __shared__ f16 Vsm[2][128][64];  // 32 KB dbuf, V^T [d][kv], 128 B rows, swizzled
  __shared__ f16 Psm[8][16][64];   // 16 KB per-wave P (wave-private)
  const int p = blockIdx.x;              // 0..1023
  const int L = (p & 7) * 128 + (p >> 3);
  const int qt = L & 7, h = (L >> 3) & 31, b = L >> 8;
  const int kvh = h >> 2;  // G = 4
  const int tid = threadIdx.x;
  const int l = tid & 63, w = tid >> 6;  // 8 waves
  const int lq = l & 15, lk = l >> 4;

  f16x8 qreg[4];
  const f16* Qbase = Qf + ((size_t)(b * 1024 + qt * 128 + w * 16)) * 4096 + h * 128;
#pragma unroll
  for (int ks = 0; ks < 4; ++ks)
    qreg[ks] = *reinterpret_cast<const f16x8*>(
        Qbase + (size_t)lq * 4096 + ks * 32 + lk * 8);

  const f16* Kb = Kf + (size_t)(b * 8 + kvh) * (1664 * 128);
  const f16* Vb = Vtf + (size_t)(b * 8 + kvh) * (128 * 1664);

  f32x4 o[8];
  f32x4 zf = {0.f, 0.f, 0.f, 0.f};
  f32x4 neg8 = {-8.f, -8.f, -8.f, -8.f};
#pragma unroll
  for (int dn = 0; dn < 8; ++dn) o[dn] = zf;
  float lrow[4];  // per-lane partial row sums, reduced once in epilogue
#pragma unroll
  for (int j = 0; j < 4; ++j) lrow[j] = 0.f;

  char* Pw = (char*)(&Psm[w][0][0]);
  const int swzR = (lq & 7) << 4;

  auto stageK = [&](int t, int buf) {
#pragma unroll
    for (int i = 0; i < 2; ++i) {
      int row = w * 8 + i * 4 + lk;
      int cb = (lq * 16) ^ ((row & 7) << 4);
      gload_lds16(Kb + (size_t)(t * 64 + row) * 128 + (cb >> 1),
                  (char*)(&Ksm[buf][0][0]) + w * 2048 + i * 1024);
    }
  };
  auto stageV = [&](int t, int buf) {
#pragma unroll
    for (int i = 0; i < 2; ++i) {
      int r = w * 16 + i * 8 + (l >> 3);
      int cb = ((l & 7) * 16) ^ ((r & 7) << 4);
      gload_lds16(Vb + (size_t)r * 1664 + t * 64 + (cb >> 1),
                  (char*)(&Vsm[buf][0][0]) + w * 2048 + i * 1024);
    }
  };

  stageK(0, 0);
  stageV(0, 0);
  int cur = 0;
  for (int t = 0; t < 26; ++t) {
    if (t < 25) {
      stageK(t + 1, cur ^ 1);
      stageV(t + 1, cur ^ 1);
      asm volatile("s_waitcnt vmcnt(4)" ::: "memory");
    } else {
      asm volatile("s_waitcnt vmcnt(0)" ::: "memory");
    }
    __builtin_amdgcn_s_barrier();

    // ---- S = Q K^T - 8 (fp32 accum, static-max offset in C-init)
    f32x4 s[4];
#pragma unroll
    for (int kn = 0; kn < 4; ++kn) s[kn] = neg8;
    __builtin_amdgcn_s_setprio(1);
#pragma unroll
    for (int ks = 0; ks < 4; ++ks) {
      f16x8 bf[4];
#pragma unroll
      for (int kn = 0; kn < 4; ++kn)
        bf[kn] = *reinterpret_cast<const f16x8*>(
            (char*)(&Ksm[cur][0][0]) + (kn * 16 + lq) * 256 + ((ks * 64 + lk * 16) ^ swzR));
#pragma unroll
      for (int kn = 0; kn < 4; ++kn)
        s[kn] = __builtin_amdgcn_mfma_f32_16x16x32_f16(qreg[ks], bf[kn], s[kn], 0, 0, 0);
    }
    __builtin_amdgcn_s_setprio(0);

    if (t == 25) {
#pragma unroll
      for (int kn = 0; kn < 4; ++kn) {
        bool valid = (kn * 16 + lq) < 1;
#pragma unroll
        for (int j = 0; j < 4; ++j) s[kn][j] = valid ? s[kn][j] : -1e30f;
      }
    }

    // ---- softmax numerator: P = 2^s (s already offset by -8); per-lane partial sums
#pragma unroll
    for (int j = 0; j < 4; ++j) {
      float rsum = 0.f;
#pragma unroll
      for (int kn = 0; kn < 4; ++kn) {
        float pv = exp2f(s[kn][j]);
        s[kn][j] = pv;
        rsum += pv;
      }
      lrow[j] += rsum;
      int prow = lk * 4 + j;
      int swzW = (prow & 7) << 4;
#pragma unroll
      for (int kn = 0; kn < 4; ++kn)
        *reinterpret_cast<f16*>(Pw + prow * 128 + (((kn * 16 + lq) * 2) ^ swzW)) =
            (f16)s[kn][j];
    }

    // ---- O += P V
    __builtin_amdgcn_s_setprio(1);
#pragma unroll
    for (int c = 0; c < 2; ++c) {
      f16x8 pa = *reinterpret_cast<const f16x8*>(
          Pw + lq * 128 + ((c * 64 + lk * 16) ^ swzR));
      f16x8 vb[8];
#pragma unroll
      for (int dn = 0; dn < 8; ++dn)
        vb[dn] = *reinterpret_cast<const f16x8*>(
            (char*)(&Vsm[cur][0][0]) + (dn * 16 + lq) * 128 + ((c * 64 + lk * 16) ^ swzR));
#pragma unroll
      for (int dn = 0; dn < 8; ++dn)
        o[dn] = __builtin_amdgcn_mfma_f32_16x16x32_f16(pa, vb[dn], o[dn], 0, 0, 0);
    }
    __builtin_amdgcn_s_setprio(0);
    __builtin_amdgcn_s_barrier();
    cur ^= 1;
  }

  // ---- epilogue: reduce lrow partials across the 16-lane row group, then O/l
#pragma unroll
  for (int j = 0; j < 4; ++j) {
    float fl = lrow[j];
    fl += __shfl_xor(fl, 1);
    fl += __shfl_xor(fl, 2);
    fl += __shfl_xor(fl, 4);
    fl += __shfl_xor(fl, 8);
    float il = 1.0f / fl;
    int token = b * 1024 + qt * 128 + w * 16 + lk * 4 + j;
    f16* dst = Oa + (size_t)token * 4096 + h * 128;
#pragma unroll
    for (int dn = 0; dn < 8; ++dn) dst[dn * 16 + lq] = (f16)(o[dn][j] * il);
  }
}

// ---------------------------------------------------------------- launch
extern "C" void kernel_launch(void* const* d_in, const int* in_sizes, int n_in,
                              void* d_out, int out_size, void* d_ws, size_t ws_size,
                              hipStream_t stream) {
  const float* hidden = (const float*)d_in[0];  // [4,1024,4096]
  const float* cross  = (const float*)d_in[1];  // [4,1601,4096]
  const float* wqkv   = (const float*)d_in[2];  // [6144,4096]
  const float* wo     = (const float*)d_in[3];  // [4096,4096]
  const float* qw     = (const float*)d_in[4];  // [128]
  const float* kw     = (const float*)d_in[5];  // [128]

  char* ws = (char*)d_ws;
  f16* hidden_h = (f16*)(ws + 0);            // 33.55 MB -> attn_h after Q-proj
  f16* attn_h   = hidden_h;
  f16* wqkv_h = (f16*)(ws + 33554432);       // 50.33 MB
  f16* cross_h = (f16*)(ws + 83886080);      // 52.46 MB -> wo_h after KV-proj
  f16* wo_h    = (f16*)(ws + 83886080);
  f16* k_h  = (f16*)(ws + 136347648);        // 13.63 MB
  f16* vt_h = (f16*)(ws + 136347648 + 13631488);  // 13.63 MB
  f16* q_h = (f16*)d_out;  // consumed by attn before O-proj overwrites d_out

  // 1) fused converts (hidden, cross, wqkv) + zero-fill of K/Vt pads
  cvtzero_kernel<<<2048, 256, 0, stream>>>(hidden, hidden_h, cross, cross_h,
                                           wqkv, wqkv_h, (float4*)(ws + 136347648));
  // 2) KV projection with fused K-RMS + V-transpose epilogue
  gemm256<true, 2><<<dim3(8, 26), 512, 0, stream>>>(
      cross_h, wqkv_h + (size_t)4096 * 4096, nullptr, k_h, kw, vt_h, 6404, 2048, 4096);
  // 3) wo convert (into dead cross_h region)
  cvt_kernel<<<2048, 256, 0, stream>>>(wo, wo_h, 16777216 / 4);
  // 4) Q projection with fused RMS-norm (+scale*log2e) -> f16 q_h (in d_out)
  gemm256<false, 1><<<dim3(16, 16), 512, 0, stream>>>(
      hidden_h, wqkv_h, nullptr, q_h, qw, nullptr, 4096, 4096, 4096);
  // 5) attention
  attn_kernel<<<1024, 512, 0, stream>>>(q_h, k_h, vt_h, attn_h);
  // 6) output projection -> d_out
  gemm256<false, 0><<<dim3(16, 16), 512, 0, stream>>>(
      attn_h, wo_h, (float*)d_out, nullptr, nullptr, nullptr, 4096, 4096, 4096);
}

// Round 12
// 613.462 us; speedup vs baseline: 1.8647x; 1.0333x over previous
//
#include <hip/hip_runtime.h>
#include <cstdint>
#include <math.h>

typedef _Float16 f16;
typedef __attribute__((ext_vector_type(4))) _Float16 f16x4;
typedef __attribute__((ext_vector_type(8))) _Float16 f16x8;
typedef __attribute__((ext_vector_type(4))) float f32x4;

// ---------------------------------------------------------------- helpers
__device__ inline void gload_lds16(const void* g, void* l) {
  auto gp = reinterpret_cast<const __attribute__((address_space(1))) uint32_t*>(
      reinterpret_cast<uintptr_t>(g));
  auto lp = reinterpret_cast<__attribute__((address_space(3))) uint32_t*>(
      reinterpret_cast<uintptr_t>(l));
  __builtin_amdgcn_global_load_lds(gp, lp, 16 /*bytes*/, 0, 0);
}

// ---------------------------------------------------------------- fused fp32->f16 converts + zero-fill
// R0 hidden (4194304 f4) R1 cross (6557696) R2 wqkv (6291456) R3 zero K/Vt (1703936 x16B)
__global__ __launch_bounds__(256) void cvtzero_kernel(const float* __restrict__ s0, f16* __restrict__ d0,
                                                      const float* __restrict__ s1, f16* __restrict__ d1,
                                                      const float* __restrict__ s2, f16* __restrict__ d2,
                                                      float4* __restrict__ z) {
  int idx = blockIdx.x * blockDim.x + threadIdx.x;
  int stride = gridDim.x * blockDim.x;
  for (int i = idx; i < 18747392; i += stride) {
    const float* src; f16* dst; int k;
    if (i < 4194304) { src = s0; dst = d0; k = i; }
    else if (i < 10752000) { src = s1; dst = d1; k = i - 4194304; }
    else if (i < 17043456) { src = s2; dst = d2; k = i - 10752000; }
    else { float4 zr = {0.f, 0.f, 0.f, 0.f}; z[i - 17043456] = zr; continue; }
    float4 v = reinterpret_cast<const float4*>(src)[k];
    f16x4 h;
    h.x = (f16)v.x; h.y = (f16)v.y; h.z = (f16)v.z; h.w = (f16)v.w;
    reinterpret_cast<f16x4*>(dst)[k] = h;
  }
}

// ---------------------------------------------------------------- plain fp32 -> f16 convert (wo)
__global__ __launch_bounds__(256) void cvt_kernel(const float* __restrict__ src,
                                                  f16* __restrict__ dst, int n4) {
  int idx = blockIdx.x * blockDim.x + threadIdx.x;
  int stride = gridDim.x * blockDim.x;
  for (int i = idx; i < n4; i += stride) {
    float4 v = reinterpret_cast<const float4*>(src)[i];
    f16x4 h;
    h.x = (f16)v.x; h.y = (f16)v.y; h.z = (f16)v.z; h.w = (f16)v.w;
    reinterpret_cast<f16x4*>(dst)[i] = h;
  }
}

// ---------------------------------------------------------------- 256x256 GEMM, m201-style 4-phase
// C[M][N] = A[M][K] * B[N][K]^T.  512 thr / 8 waves (2M x 4N), per-wave 128x64,
// BK=64, LDS 128 KB dbuf.  Per K-tile: 4 phases, ONE barrier each; every
// phase's ds_reads + 2 staging issues are hoisted BEFORE the preceding barrier
// so they overlap the previous MFMA cluster.  Intra-tile trailing barriers are
// redundant (staging targets nbuf; all staging ordered after the entry
// barrier which syncs the last reads of nbuf's old tile).  Counted vmcnt(2)
// at tile entry only.  setprio around MFMA clusters.
// EPI==0: fp32 C.  EPI==1: per-128-col RMS -> f16 Ch (Q path, scale*log2e).
// EPI==2: KV path (K-half: RMS -> Kf; V-half: transpose -> Vtf).
template <bool MB, int EPI>
__global__ __launch_bounds__(512, 2) void gemm256(const f16* __restrict__ A,
                                                  const f16* __restrict__ Bw,
                                                  float* __restrict__ C,
                                                  f16* __restrict__ Ch,
                                                  const float* __restrict__ wvec,
                                                  f16* __restrict__ Vtf,
                                                  int M, int N, int K) {
  __shared__ f16 As[2][256][64];
  __shared__ f16 Bs[2][256][64];
  const int tid = threadIdx.x;
  const int l = tid & 63, w = tid >> 6;  // 8 waves
  const int lq = l & 15, lk = l >> 4;
  const int wm = w >> 2, wn = w & 3;     // 2M x 4N wave grid
  // XCD-aware bijective swizzle (nwg % 8 == 0 for all grids used)
  const int nwg = gridDim.x * gridDim.y;
  const int p = blockIdx.y * gridDim.x + blockIdx.x;
  const int L = (p & 7) * (nwg >> 3) + (p >> 3);
  const int bx = L % gridDim.x, by = L / gridDim.x;
  const int brow = by * 256, bcol = bx * 256;
  const int KT = K >> 6;

  const int srow8 = w * 8 + (l >> 3);            // + i*64
  const int scol  = ((l & 7) ^ (l >> 3)) * 8;    // pre-swizzled source col (f16)
  const int swz   = (lq & 7) << 4;               // read-side XOR

  f32x4 acc[8][4];
  f32x4 zf = {0.f, 0.f, 0.f, 0.f};
#pragma unroll
  for (int m = 0; m < 8; ++m)
#pragma unroll
    for (int n = 0; n < 4; ++n) acc[m][n] = zf;

  auto stageA = [&](int kt, int buf, int i) {
    int ra = brow + i * 64 + srow8;
    if (MB) ra = (ra < M) ? ra : (M - 1);
    gload_lds16(A + (size_t)ra * K + kt * 64 + scol,
                (char*)(&As[buf][0][0]) + i * 8192 + w * 1024);
  };
  auto stageB = [&](int kt, int buf, int i) {
    int rb = bcol + i * 64 + srow8;
    gload_lds16(Bw + (size_t)rb * K + kt * 64 + scol,
                (char*)(&Bs[buf][0][0]) + i * 8192 + w * 1024);
  };
  auto ldA = [&](int buf, int m, int kk) -> f16x8 {
    int r = wm * 128 + m * 16 + lq;
    return *reinterpret_cast<const f16x8*>(
        (char*)(&As[buf][0][0]) + r * 128 + ((kk * 64 + lk * 16) ^ swz));
  };
  auto ldB = [&](int buf, int n, int kk) -> f16x8 {
    int r = wn * 64 + n * 16 + lq;
    return *reinterpret_cast<const f16x8*>(
        (char*)(&Bs[buf][0][0]) + r * 128 + ((kk * 64 + lk * 16) ^ swz));
  };

  // prologue: stage tile 0 (8 issues)
#pragma unroll
  for (int i = 0; i < 4; ++i) stageA(0, 0, i);
#pragma unroll
  for (int i = 0; i < 4; ++i) stageB(0, 0, i);

  f16x8 avA[4][2], avB[4][2], bvA[2][2], bvB[2][2];
  for (int t = 0; t < KT; ++t) {
    const int buf = t & 1, nbuf = buf ^ 1;
    const bool pf = (t + 1 < KT);

    // ---- tile entry: 2 stages ahead, then wait for tile-t's 8
    if (pf) {
      stageA(t + 1, nbuf, 0); stageA(t + 1, nbuf, 1);
      asm volatile("s_waitcnt vmcnt(2)" ::: "memory");
    } else {
      asm volatile("s_waitcnt vmcnt(0)" ::: "memory");
    }
    __builtin_amdgcn_s_barrier();

    // ---- phase 0: (m0-3 x n0-1); loads exposed (buf just became valid)
#pragma unroll
    for (int mm = 0; mm < 4; ++mm)
#pragma unroll
      for (int kk = 0; kk < 2; ++kk) avA[mm][kk] = ldA(buf, mm, kk);
#pragma unroll
    for (int nn = 0; nn < 2; ++nn)
#pragma unroll
      for (int kk = 0; kk < 2; ++kk) bvA[nn][kk] = ldB(buf, nn, kk);
    __builtin_amdgcn_s_setprio(1);
#pragma unroll
    for (int mm = 0; mm < 4; ++mm)
#pragma unroll
      for (int nn = 0; nn < 2; ++nn)
#pragma unroll
        for (int kk = 0; kk < 2; ++kk)
          acc[mm][nn] = __builtin_amdgcn_mfma_f32_16x16x32_f16(avA[mm][kk], bvA[nn][kk], acc[mm][nn], 0, 0, 0);
    __builtin_amdgcn_s_setprio(0);
    // pre-phase-1: loads + stages overlap phase-0 MFMAs
#pragma unroll
    for (int mm = 0; mm < 4; ++mm)
#pragma unroll
      for (int kk = 0; kk < 2; ++kk) avB[mm][kk] = ldA(buf, 4 + mm, kk);
    if (pf) { stageA(t + 1, nbuf, 2); stageA(t + 1, nbuf, 3); }
    asm volatile("" ::: "memory");
    __builtin_amdgcn_s_barrier();

    // ---- phase 1: (m4-7 x n0-1)
    __builtin_amdgcn_s_setprio(1);
#pragma unroll
    for (int mm = 0; mm < 4; ++mm)
#pragma unroll
      for (int nn = 0; nn < 2; ++nn)
#pragma unroll
        for (int kk = 0; kk < 2; ++kk)
          acc[4 + mm][nn] = __builtin_amdgcn_mfma_f32_16x16x32_f16(avB[mm][kk], bvA[nn][kk], acc[4 + mm][nn], 0, 0, 0);
    __builtin_amdgcn_s_setprio(0);
#pragma unroll
    for (int nn = 0; nn < 2; ++nn)
#pragma unroll
      for (int kk = 0; kk < 2; ++kk) bvB[nn][kk] = ldB(buf, 2 + nn, kk);
    if (pf) { stageB(t + 1, nbuf, 0); stageB(t + 1, nbuf, 1); }
    asm volatile("" ::: "memory");
    __builtin_amdgcn_s_barrier();

    // ---- phase 2: (m4-7 x n2-3)
    __builtin_amdgcn_s_setprio(1);
#pragma unroll
    for (int mm = 0; mm < 4; ++mm)
#pragma unroll
      for (int nn = 0; nn < 2; ++nn)
#pragma unroll
        for (int kk = 0; kk < 2; ++kk)
          acc[4 + mm][2 + nn] = __builtin_amdgcn_mfma_f32_16x16x32_f16(avB[mm][kk], bvB[nn][kk], acc[4 + mm][2 + nn], 0, 0, 0);
    __builtin_amdgcn_s_setprio(0);
#pragma unroll
    for (int mm = 0; mm < 4; ++mm)
#pragma unroll
      for (int kk = 0; kk < 2; ++kk) avA[mm][kk] = ldA(buf, mm, kk);
    if (pf) { stageB(t + 1, nbuf, 2); stageB(t + 1, nbuf, 3); }
    asm volatile("" ::: "memory");
    __builtin_amdgcn_s_barrier();

    // ---- phase 3: (m0-3 x n2-3)
    __builtin_amdgcn_s_setprio(1);
#pragma unroll
    for (int mm = 0; mm < 4; ++mm)
#pragma unroll
      for (int nn = 0; nn < 2; ++nn)
#pragma unroll
        for (int kk = 0; kk < 2; ++kk)
          acc[mm][2 + nn] = __builtin_amdgcn_mfma_f32_16x16x32_f16(avA[mm][kk], bvB[nn][kk], acc[mm][2 + nn], 0, 0, 0);
    __builtin_amdgcn_s_setprio(0);
  }

  if (EPI == 0) {
#pragma unroll
    for (int m = 0; m < 8; ++m) {
#pragma unroll
      for (int j = 0; j < 4; ++j) {
        int row = brow + wm * 128 + m * 16 + lk * 4 + j;
        if (MB && row >= M) continue;
        float* dst = C + (size_t)row * N + bcol + wn * 64 + lq;
#pragma unroll
        for (int n = 0; n < 4; ++n) dst[n * 16] = acc[m][n][j];
      }
    }
  } else if (EPI == 1) {
    // fused RMS over each 128-col head group (tile spans 2 heads)
    __shared__ float ssq[256][4];
#pragma unroll
    for (int m = 0; m < 8; ++m)
#pragma unroll
      for (int j = 0; j < 4; ++j) {
        int lr = wm * 128 + m * 16 + lk * 4 + j;
        float pp = 0.f;
#pragma unroll
        for (int n = 0; n < 4; ++n) pp += acc[m][n][j] * acc[m][n][j];
        pp += __shfl_xor(pp, 1);
        pp += __shfl_xor(pp, 2);
        pp += __shfl_xor(pp, 4);
        pp += __shfl_xor(pp, 8);
        if (lq == 0) ssq[lr][wn] = pp;
      }
    asm volatile("" ::: "memory");
    __builtin_amdgcn_s_barrier();
    const int hh = wn >> 1;
    float wv[4];
#pragma unroll
    for (int n = 0; n < 4; ++n) wv[n] = wvec[(wn * 64 + n * 16 + lq) & 127];
#pragma unroll
    for (int m = 0; m < 8; ++m)
#pragma unroll
      for (int j = 0; j < 4; ++j) {
        int lr = wm * 128 + m * 16 + lk * 4 + j;
        float ss = ssq[lr][hh * 2] + ssq[lr][hh * 2 + 1];
        float rs = rsqrtf(ss * (1.0f / 128.0f) + 1e-5f) *
                   (0.08838834764831845f * 1.4426950408889634f);
        f16* dst = Ch + (size_t)(brow + lr) * N + bcol + wn * 64 + lq;
#pragma unroll
        for (int n = 0; n < 4; ++n) dst[n * 16] = (f16)(acc[m][n][j] * rs * wv[n]);
      }
  } else {
    // EPI==2: KV path.  rows r = b*1601+s (M=6404); K half: RMS -> Kf; V half -> Vtf^T
    const bool isK = (bcol < 1024);
    __shared__ float ssq[256][4];
    if (isK) {
#pragma unroll
      for (int m = 0; m < 8; ++m)
#pragma unroll
        for (int j = 0; j < 4; ++j) {
          int lr = wm * 128 + m * 16 + lk * 4 + j;
          float pp = 0.f;
#pragma unroll
          for (int n = 0; n < 4; ++n) pp += acc[m][n][j] * acc[m][n][j];
          pp += __shfl_xor(pp, 1);
          pp += __shfl_xor(pp, 2);
          pp += __shfl_xor(pp, 4);
          pp += __shfl_xor(pp, 8);
          if (lq == 0) ssq[lr][wn] = pp;
        }
      asm volatile("" ::: "memory");
      __builtin_amdgcn_s_barrier();
    }
    const int hh = wn >> 1;
    float wv[4];
    if (isK) {
#pragma unroll
      for (int n = 0; n < 4; ++n) wv[n] = wvec[(wn * 64 + n * 16 + lq) & 127];
    }
#pragma unroll
    for (int m = 0; m < 8; ++m) {
#pragma unroll
      for (int j = 0; j < 4; ++j) {
        int lr = wm * 128 + m * 16 + lk * 4 + j;
        int r = brow + lr;
        if (r >= M) continue;
        unsigned bb = (unsigned)r / 1601u;
        unsigned s = (unsigned)r - bb * 1601u;
        if (isK) {
          float ss = ssq[lr][hh * 2] + ssq[lr][hh * 2 + 1];
          float rs = rsqrtf(ss * (1.0f / 128.0f) + 1e-5f);
#pragma unroll
          for (int n = 0; n < 4; ++n) {
            int col = wn * 64 + n * 16 + lq;
            int kvh = (bcol + col) >> 7;
            int d = col & 127;
            Ch[((size_t)(bb * 8 + kvh) * 1664 + s) * 128 + d] =
                (f16)(acc[m][n][j] * rs * wv[n]);
          }
        } else {
#pragma unroll
          for (int n = 0; n < 4; ++n) {
            int col = bcol - 1024 + wn * 64 + n * 16 + lq;
            int kvh = col >> 7;
            int d = col & 127;
            Vtf[((size_t)(bb * 8 + kvh) * 128 + d) * 1664 + s] = (f16)acc[m][n][j];
          }
        }
      }
    }
  }
}

// ---------------------------------------------------------------- flash attention (r11 state, 173 us)
// QBLK=128 as 8 waves x 16 q rows (512-thread block), KVBLK=64.  LDS 80 KB.
// STATIC-MAX softmax (|logit| <= 16.33 bounded by RMS norms; offset -8 in C-init).
__global__ __launch_bounds__(512, 4) void attn_kernel(const f16* __restrict__ Qf,
                                                      const f16* __restrict__ Kf,
                                                      const f16* __restrict__ Vtf,
                                                      f16* __restrict__ Oa) {
  __shared__ f16 Ksm[2][64][128];  // 32 KB dbuf, 256 B rows, XOR-swizzled
  __shared__ f16 Vsm[2][128][64];  // 32 KB dbuf, V^T [d][kv], 128 B rows, swizzled
  __shared__ f16 Psm[8][16][64];   // 16 KB per-wave P (wave-private)
  const int p = blockIdx.x;              // 0..1023
  const int L = (p & 7) * 128 + (p >> 3);
  const int qt = L & 7, h = (L >> 3) & 31, b = L >> 8;
  const int kvh = h >> 2;  // G = 4
  const int tid = threadIdx.x;
  const int l = tid & 63, w = tid >> 6;  // 8 waves
  const int lq = l & 15, lk = l >> 4;

  f16x8 qreg[4];
  const f16* Qbase = Qf + ((size_t)(b * 1024 + qt * 128 + w * 16)) * 4096 + h * 128;
#pragma unroll
  for (int ks = 0; ks < 4; ++ks)
    qreg[ks] = *reinterpret_cast<const f16x8*>(
        Qbase + (size_t)lq * 4096 + ks * 32 + lk * 8);

  const f16* Kb = Kf + (size_t)(b * 8 + kvh) * (1664 * 128);
  const f16* Vb = Vtf + (size_t)(b * 8 + kvh) * (128 * 1664);

  f32x4 o[8];
  f32x4 zf = {0.f, 0.f, 0.f, 0.f};
  f32x4 neg8 = {-8.f, -8.f, -8.f, -8.f};
#pragma unroll
  for (int dn = 0; dn < 8; ++dn) o[dn] = zf;
  float lrow[4];  // per-lane partial row sums, reduced once in epilogue
#pragma unroll
  for (int j = 0; j < 4; ++j) lrow[j] = 0.f;

  char* Pw = (char*)(&Psm[w][0][0]);
  const int swzR = (lq & 7) << 4;

  auto stageK = [&](int t, int buf) {
#pragma unroll
    for (int i = 0; i < 2; ++i) {
      int row = w * 8 + i * 4 + lk;
      int cb = (lq * 16) ^ ((row & 7) << 4);
      gload_lds16(Kb + (size_t)(t * 64 + row) * 128 + (cb >> 1),
                  (char*)(&Ksm[buf][0][0]) + w * 2048 + i * 1024);
    }
  };
  auto stageV = [&](int t, int buf) {
#pragma unroll
    for (int i = 0; i < 2; ++i) {
      int r = w * 16 + i * 8 + (l >> 3);
      int cb = ((l & 7) * 16) ^ ((r & 7) << 4);
      gload_lds16(Vb + (size_t)r * 1664 + t * 64 + (cb >> 1),
                  (char*)(&Vsm[buf][0][0]) + w * 2048 + i * 1024);
    }
  };

  stageK(0, 0);
  stageV(0, 0);
  int cur = 0;
  for (int t = 0; t < 26; ++t) {
    if (t < 25) {
      stageK(t + 1, cur ^ 1);
      stageV(t + 1, cur ^ 1);
      asm volatile("s_waitcnt vmcnt(4)" ::: "memory");
    } else {
      asm volatile("s_waitcnt vmcnt(0)" ::: "memory");
    }
    __builtin_amdgcn_s_barrier();

    // ---- S = Q K^T - 8 (fp32 accum, static-max offset in C-init)
    f32x4 s[4];
#pragma unroll
    for (int kn = 0; kn < 4; ++kn) s[kn] = neg8;
    __builtin_amdgcn_s_setprio(1);
#pragma unroll
    for (int ks = 0; ks < 4; ++ks) {
      f16x8 bf[4];
#pragma unroll
      for (int kn = 0; kn < 4; ++kn)
        bf[kn] = *reinterpret_cast<const f16x8*>(
            (char*)(&Ksm[cur][0][0]) + (kn * 16 + lq) * 256 + ((ks * 64 + lk * 16) ^ swzR));
#pragma unroll
      for (int kn = 0; kn < 4; ++kn)
        s[kn] = __builtin_amdgcn_mfma_f32_16x16x32_f16(qreg[ks], bf[kn], s[kn], 0, 0, 0);
    }
    __builtin_amdgcn_s_setprio(0);

    if (t == 25) {
#pragma unroll
      for (int kn = 0; kn < 4; ++kn) {
        bool valid = (kn * 16 + lq) < 1;
#pragma unroll
        for (int j = 0; j < 4; ++j) s[kn][j] = valid ? s[kn][j] : -1e30f;
      }
    }

    // ---- softmax numerator: P = 2^s; per-lane partial sums
#pragma unroll
    for (int j = 0; j < 4; ++j) {
      float rsum = 0.f;
#pragma unroll
      for (int kn = 0; kn < 4; ++kn) {
        float pv = exp2f(s[kn][j]);
        s[kn][j] = pv;
        rsum += pv;
      }
      lrow[j] += rsum;
      int prow = lk * 4 + j;
      int swzW = (prow & 7) << 4;
#pragma unroll
      for (int kn = 0; kn < 4; ++kn)
        *reinterpret_cast<f16*>(Pw + prow * 128 + (((kn * 16 + lq) * 2) ^ swzW)) =
            (f16)s[kn][j];
    }

    // ---- O += P V
    __builtin_amdgcn_s_setprio(1);
#pragma unroll
    for (int c = 0; c < 2; ++c) {
      f16x8 pa = *reinterpret_cast<const f16x8*>(
          Pw + lq * 128 + ((c * 64 + lk * 16) ^ swzR));
      f16x8 vb[8];
#pragma unroll
      for (int dn = 0; dn < 8; ++dn)
        vb[dn] = *reinterpret_cast<const f16x8*>(
            (char*)(&Vsm[cur][0][0]) + (dn * 16 + lq) * 128 + ((c * 64 + lk * 16) ^ swzR));
#pragma unroll
      for (int dn = 0; dn < 8; ++dn)
        o[dn] = __builtin_amdgcn_mfma_f32_16x16x32_f16(pa, vb[dn], o[dn], 0, 0, 0);
    }
    __builtin_amdgcn_s_setprio(0);
    __builtin_amdgcn_s_barrier();
    cur ^= 1;
  }

  // ---- epilogue: reduce lrow partials across the 16-lane row group, then O/l
#pragma unroll
  for (int j = 0; j < 4; ++j) {
    float fl = lrow[j];
    fl += __shfl_xor(fl, 1);
    fl += __shfl_xor(fl, 2);
    fl += __shfl_xor(fl, 4);
    fl += __shfl_xor(fl, 8);
    float il = 1.0f / fl;
    int token = b * 1024 + qt * 128 + w * 16 + lk * 4 + j;
    f16* dst = Oa + (size_t)token * 4096 + h * 128;
#pragma unroll
    for (int dn = 0; dn < 8; ++dn) dst[dn * 16 + lq] = (f16)(o[dn][j] * il);
  }
}

// ---------------------------------------------------------------- launch
extern "C" void kernel_launch(void* const* d_in, const int* in_sizes, int n_in,
                              void* d_out, int out_size, void* d_ws, size_t ws_size,
                              hipStream_t stream) {
  const float* hidden = (const float*)d_in[0];  // [4,1024,4096]
  const float* cross  = (const float*)d_in[1];  // [4,1601,4096]
  const float* wqkv   = (const float*)d_in[2];  // [6144,4096]
  const float* wo     = (const float*)d_in[3];  // [4096,4096]
  const float* qw     = (const float*)d_in[4];  // [128]
  const float* kw     = (const float*)d_in[5];  // [128]

  char* ws = (char*)d_ws;
  f16* hidden_h = (f16*)(ws + 0);            // 33.55 MB -> attn_h after Q-proj
  f16* attn_h   = hidden_h;
  f16* wqkv_h = (f16*)(ws + 33554432);       // 50.33 MB
  f16* cross_h = (f16*)(ws + 83886080);      // 52.46 MB -> wo_h after KV-proj
  f16* wo_h    = (f16*)(ws + 83886080);
  f16* k_h  = (f16*)(ws + 136347648);        // 13.63 MB
  f16* vt_h = (f16*)(ws + 136347648 + 13631488);  // 13.63 MB
  f16* q_h = (f16*)d_out;  // consumed by attn before O-proj overwrites d_out

  // 1) fused converts (hidden, cross, wqkv) + zero-fill of K/Vt pads
  cvtzero_kernel<<<2048, 256, 0, stream>>>(hidden, hidden_h, cross, cross_h,
                                           wqkv, wqkv_h, (float4*)(ws + 136347648));
  // 2) KV projection with fused K-RMS + V-transpose epilogue
  gemm256<true, 2><<<dim3(8, 26), 512, 0, stream>>>(
      cross_h, wqkv_h + (size_t)4096 * 4096, nullptr, k_h, kw, vt_h, 6404, 2048, 4096);
  // 3) wo convert (into dead cross_h region)
  cvt_kernel<<<2048, 256, 0, stream>>>(wo, wo_h, 16777216 / 4);
  // 4) Q projection with fused RMS-norm (+scale*log2e) -> f16 q_h (in d_out)
  gemm256<false, 1><<<dim3(16, 16), 512, 0, stream>>>(
      hidden_h, wqkv_h, nullptr, q_h, qw, nullptr, 4096, 4096, 4096);
  // 5) attention
  attn_kernel<<<1024, 512, 0, stream>>>(q_h, k_h, vt_h, attn_h);
  // 6) output projection -> d_out
  gemm256<false, 0><<<dim3(16, 16), 512, 0, stream>>>(
      attn_h, wo_h, (float*)d_out, nullptr, nullptr, nullptr, 4096, 4096, 4096);
}

// Round 13
// 605.680 us; speedup vs baseline: 1.8887x; 1.0128x over previous
//
#include <hip/hip_runtime.h>
#include <cstdint>
#include <math.h>

typedef _Float16 f16;
typedef __attribute__((ext_vector_type(4))) _Float16 f16x4;
typedef __attribute__((ext_vector_type(8))) _Float16 f16x8;
typedef __attribute__((ext_vector_type(4))) float f32x4;

// ---------------------------------------------------------------- helpers
__device__ inline void gload_lds16(const void* g, void* l) {
  auto gp = reinterpret_cast<const __attribute__((address_space(1))) uint32_t*>(
      reinterpret_cast<uintptr_t>(g));
  auto lp = reinterpret_cast<__attribute__((address_space(3))) uint32_t*>(
      reinterpret_cast<uintptr_t>(l));
  __builtin_amdgcn_global_load_lds(gp, lp, 16 /*bytes*/, 0, 0);
}

// ---------------------------------------------------------------- fused fp32->f16 converts + zero-fill
// R0 hidden (4194304 f4) R1 cross (6557696) R2 wqkv (6291456) R3 zero K/Vt (1703936 x16B)
__global__ __launch_bounds__(256) void cvtzero_kernel(const float* __restrict__ s0, f16* __restrict__ d0,
                                                      const float* __restrict__ s1, f16* __restrict__ d1,
                                                      const float* __restrict__ s2, f16* __restrict__ d2,
                                                      float4* __restrict__ z) {
  int idx = blockIdx.x * blockDim.x + threadIdx.x;
  int stride = gridDim.x * blockDim.x;
  for (int i = idx; i < 18747392; i += stride) {
    const float* src; f16* dst; int k;
    if (i < 4194304) { src = s0; dst = d0; k = i; }
    else if (i < 10752000) { src = s1; dst = d1; k = i - 4194304; }
    else if (i < 17043456) { src = s2; dst = d2; k = i - 10752000; }
    else { float4 zr = {0.f, 0.f, 0.f, 0.f}; z[i - 17043456] = zr; continue; }
    float4 v = reinterpret_cast<const float4*>(src)[k];
    f16x4 h;
    h.x = (f16)v.x; h.y = (f16)v.y; h.z = (f16)v.z; h.w = (f16)v.w;
    reinterpret_cast<f16x4*>(dst)[k] = h;
  }
}

// ---------------------------------------------------------------- plain fp32 -> f16 convert (wo)
__global__ __launch_bounds__(256) void cvt_kernel(const float* __restrict__ src,
                                                  f16* __restrict__ dst, int n4) {
  int idx = blockIdx.x * blockDim.x + threadIdx.x;
  int stride = gridDim.x * blockDim.x;
  for (int i = idx; i < n4; i += stride) {
    float4 v = reinterpret_cast<const float4*>(src)[i];
    f16x4 h;
    h.x = (f16)v.x; h.y = (f16)v.y; h.z = (f16)v.z; h.w = (f16)v.w;
    reinterpret_cast<f16x4*>(dst)[i] = h;
  }
}

// ---------------------------------------------------------------- 256x256 GEMM, m201-style 4-phase
// (r12 state -- verified) 512 thr / 8 waves (2M x 4N), per-wave 128x64, BK=64,
// LDS 128 KB dbuf, ONE barrier/phase with hoisted ds_reads + staging, counted
// vmcnt(2) at tile entry, setprio around MFMA clusters.
// EPI==0: fp32 C.  EPI==1: per-128-col RMS -> f16 Ch (Q path, scale*log2e).
// EPI==2: KV path (K-half: RMS -> Kf; V-half: transpose -> Vtf).
template <bool MB, int EPI>
__global__ __launch_bounds__(512, 2) void gemm256(const f16* __restrict__ A,
                                                  const f16* __restrict__ Bw,
                                                  float* __restrict__ C,
                                                  f16* __restrict__ Ch,
                                                  const float* __restrict__ wvec,
                                                  f16* __restrict__ Vtf,
                                                  int M, int N, int K) {
  __shared__ f16 As[2][256][64];
  __shared__ f16 Bs[2][256][64];
  const int tid = threadIdx.x;
  const int l = tid & 63, w = tid >> 6;  // 8 waves
  const int lq = l & 15, lk = l >> 4;
  const int wm = w >> 2, wn = w & 3;     // 2M x 4N wave grid
  const int nwg = gridDim.x * gridDim.y;
  const int p = blockIdx.y * gridDim.x + blockIdx.x;
  const int L = (p & 7) * (nwg >> 3) + (p >> 3);
  const int bx = L % gridDim.x, by = L / gridDim.x;
  const int brow = by * 256, bcol = bx * 256;
  const int KT = K >> 6;

  const int srow8 = w * 8 + (l >> 3);            // + i*64
  const int scol  = ((l & 7) ^ (l >> 3)) * 8;    // pre-swizzled source col (f16)
  const int swz   = (lq & 7) << 4;               // read-side XOR

  f32x4 acc[8][4];
  f32x4 zf = {0.f, 0.f, 0.f, 0.f};
#pragma unroll
  for (int m = 0; m < 8; ++m)
#pragma unroll
    for (int n = 0; n < 4; ++n) acc[m][n] = zf;

  auto stageA = [&](int kt, int buf, int i) {
    int ra = brow + i * 64 + srow8;
    if (MB) ra = (ra < M) ? ra : (M - 1);
    gload_lds16(A + (size_t)ra * K + kt * 64 + scol,
                (char*)(&As[buf][0][0]) + i * 8192 + w * 1024);
  };
  auto stageB = [&](int kt, int buf, int i) {
    int rb = bcol + i * 64 + srow8;
    gload_lds16(Bw + (size_t)rb * K + kt * 64 + scol,
                (char*)(&Bs[buf][0][0]) + i * 8192 + w * 1024);
  };
  auto ldA = [&](int buf, int m, int kk) -> f16x8 {
    int r = wm * 128 + m * 16 + lq;
    return *reinterpret_cast<const f16x8*>(
        (char*)(&As[buf][0][0]) + r * 128 + ((kk * 64 + lk * 16) ^ swz));
  };
  auto ldB = [&](int buf, int n, int kk) -> f16x8 {
    int r = wn * 64 + n * 16 + lq;
    return *reinterpret_cast<const f16x8*>(
        (char*)(&Bs[buf][0][0]) + r * 128 + ((kk * 64 + lk * 16) ^ swz));
  };

  // prologue: stage tile 0 (8 issues)
#pragma unroll
  for (int i = 0; i < 4; ++i) stageA(0, 0, i);
#pragma unroll
  for (int i = 0; i < 4; ++i) stageB(0, 0, i);

  f16x8 avA[4][2], avB[4][2], bvA[2][2], bvB[2][2];
  for (int t = 0; t < KT; ++t) {
    const int buf = t & 1, nbuf = buf ^ 1;
    const bool pf = (t + 1 < KT);

    // ---- tile entry: 2 stages ahead, then wait for tile-t's 8
    if (pf) {
      stageA(t + 1, nbuf, 0); stageA(t + 1, nbuf, 1);
      asm volatile("s_waitcnt vmcnt(2)" ::: "memory");
    } else {
      asm volatile("s_waitcnt vmcnt(0)" ::: "memory");
    }
    __builtin_amdgcn_s_barrier();

    // ---- phase 0: (m0-3 x n0-1)
#pragma unroll
    for (int mm = 0; mm < 4; ++mm)
#pragma unroll
      for (int kk = 0; kk < 2; ++kk) avA[mm][kk] = ldA(buf, mm, kk);
#pragma unroll
    for (int nn = 0; nn < 2; ++nn)
#pragma unroll
      for (int kk = 0; kk < 2; ++kk) bvA[nn][kk] = ldB(buf, nn, kk);
    __builtin_amdgcn_s_setprio(1);
#pragma unroll
    for (int mm = 0; mm < 4; ++mm)
#pragma unroll
      for (int nn = 0; nn < 2; ++nn)
#pragma unroll
        for (int kk = 0; kk < 2; ++kk)
          acc[mm][nn] = __builtin_amdgcn_mfma_f32_16x16x32_f16(avA[mm][kk], bvA[nn][kk], acc[mm][nn], 0, 0, 0);
    __builtin_amdgcn_s_setprio(0);
#pragma unroll
    for (int mm = 0; mm < 4; ++mm)
#pragma unroll
      for (int kk = 0; kk < 2; ++kk) avB[mm][kk] = ldA(buf, 4 + mm, kk);
    if (pf) { stageA(t + 1, nbuf, 2); stageA(t + 1, nbuf, 3); }
    asm volatile("" ::: "memory");
    __builtin_amdgcn_s_barrier();

    // ---- phase 1: (m4-7 x n0-1)
    __builtin_amdgcn_s_setprio(1);
#pragma unroll
    for (int mm = 0; mm < 4; ++mm)
#pragma unroll
      for (int nn = 0; nn < 2; ++nn)
#pragma unroll
        for (int kk = 0; kk < 2; ++kk)
          acc[4 + mm][nn] = __builtin_amdgcn_mfma_f32_16x16x32_f16(avB[mm][kk], bvA[nn][kk], acc[4 + mm][nn], 0, 0, 0);
    __builtin_amdgcn_s_setprio(0);
#pragma unroll
    for (int nn = 0; nn < 2; ++nn)
#pragma unroll
      for (int kk = 0; kk < 2; ++kk) bvB[nn][kk] = ldB(buf, 2 + nn, kk);
    if (pf) { stageB(t + 1, nbuf, 0); stageB(t + 1, nbuf, 1); }
    asm volatile("" ::: "memory");
    __builtin_amdgcn_s_barrier();

    // ---- phase 2: (m4-7 x n2-3)
    __builtin_amdgcn_s_setprio(1);
#pragma unroll
    for (int mm = 0; mm < 4; ++mm)
#pragma unroll
      for (int nn = 0; nn < 2; ++nn)
#pragma unroll
        for (int kk = 0; kk < 2; ++kk)
          acc[4 + mm][2 + nn] = __builtin_amdgcn_mfma_f32_16x16x32_f16(avB[mm][kk], bvB[nn][kk], acc[4 + mm][2 + nn], 0, 0, 0);
    __builtin_amdgcn_s_setprio(0);
#pragma unroll
    for (int mm = 0; mm < 4; ++mm)
#pragma unroll
      for (int kk = 0; kk < 2; ++kk) avA[mm][kk] = ldA(buf, mm, kk);
    if (pf) { stageB(t + 1, nbuf, 2); stageB(t + 1, nbuf, 3); }
    asm volatile("" ::: "memory");
    __builtin_amdgcn_s_barrier();

    // ---- phase 3: (m0-3 x n2-3)
    __builtin_amdgcn_s_setprio(1);
#pragma unroll
    for (int mm = 0; mm < 4; ++mm)
#pragma unroll
      for (int nn = 0; nn < 2; ++nn)
#pragma unroll
        for (int kk = 0; kk < 2; ++kk)
          acc[mm][2 + nn] = __builtin_amdgcn_mfma_f32_16x16x32_f16(avA[mm][kk], bvB[nn][kk], acc[mm][2 + nn], 0, 0, 0);
    __builtin_amdgcn_s_setprio(0);
  }

  if (EPI == 0) {
#pragma unroll
    for (int m = 0; m < 8; ++m) {
#pragma unroll
      for (int j = 0; j < 4; ++j) {
        int row = brow + wm * 128 + m * 16 + lk * 4 + j;
        if (MB && row >= M) continue;
        float* dst = C + (size_t)row * N + bcol + wn * 64 + lq;
#pragma unroll
        for (int n = 0; n < 4; ++n) dst[n * 16] = acc[m][n][j];
      }
    }
  } else if (EPI == 1) {
    __shared__ float ssq[256][4];
#pragma unroll
    for (int m = 0; m < 8; ++m)
#pragma unroll
      for (int j = 0; j < 4; ++j) {
        int lr = wm * 128 + m * 16 + lk * 4 + j;
        float pp = 0.f;
#pragma unroll
        for (int n = 0; n < 4; ++n) pp += acc[m][n][j] * acc[m][n][j];
        pp += __shfl_xor(pp, 1);
        pp += __shfl_xor(pp, 2);
        pp += __shfl_xor(pp, 4);
        pp += __shfl_xor(pp, 8);
        if (lq == 0) ssq[lr][wn] = pp;
      }
    asm volatile("" ::: "memory");
    __builtin_amdgcn_s_barrier();
    const int hh = wn >> 1;
    float wv[4];
#pragma unroll
    for (int n = 0; n < 4; ++n) wv[n] = wvec[(wn * 64 + n * 16 + lq) & 127];
#pragma unroll
    for (int m = 0; m < 8; ++m)
#pragma unroll
      for (int j = 0; j < 4; ++j) {
        int lr = wm * 128 + m * 16 + lk * 4 + j;
        float ss = ssq[lr][hh * 2] + ssq[lr][hh * 2 + 1];
        float rs = rsqrtf(ss * (1.0f / 128.0f) + 1e-5f) *
                   (0.08838834764831845f * 1.4426950408889634f);
        f16* dst = Ch + (size_t)(brow + lr) * N + bcol + wn * 64 + lq;
#pragma unroll
        for (int n = 0; n < 4; ++n) dst[n * 16] = (f16)(acc[m][n][j] * rs * wv[n]);
      }
  } else {
    // EPI==2: KV path.  rows r = b*1601+s (M=6404); K half: RMS -> Kf; V half -> Vtf^T
    const bool isK = (bcol < 1024);
    __shared__ float ssq[256][4];
    if (isK) {
#pragma unroll
      for (int m = 0; m < 8; ++m)
#pragma unroll
        for (int j = 0; j < 4; ++j) {
          int lr = wm * 128 + m * 16 + lk * 4 + j;
          float pp = 0.f;
#pragma unroll
          for (int n = 0; n < 4; ++n) pp += acc[m][n][j] * acc[m][n][j];
          pp += __shfl_xor(pp, 1);
          pp += __shfl_xor(pp, 2);
          pp += __shfl_xor(pp, 4);
          pp += __shfl_xor(pp, 8);
          if (lq == 0) ssq[lr][wn] = pp;
        }
      asm volatile("" ::: "memory");
      __builtin_amdgcn_s_barrier();
    }
    const int hh = wn >> 1;
    float wv[4];
    if (isK) {
#pragma unroll
      for (int n = 0; n < 4; ++n) wv[n] = wvec[(wn * 64 + n * 16 + lq) & 127];
    }
#pragma unroll
    for (int m = 0; m < 8; ++m) {
#pragma unroll
      for (int j = 0; j < 4; ++j) {
        int lr = wm * 128 + m * 16 + lk * 4 + j;
        int r = brow + lr;
        if (r >= M) continue;
        unsigned bb = (unsigned)r / 1601u;
        unsigned s = (unsigned)r - bb * 1601u;
        if (isK) {
          float ss = ssq[lr][hh * 2] + ssq[lr][hh * 2 + 1];
          float rs = rsqrtf(ss * (1.0f / 128.0f) + 1e-5f);
#pragma unroll
          for (int n = 0; n < 4; ++n) {
            int col = wn * 64 + n * 16 + lq;
            int kvh = (bcol + col) >> 7;
            int d = col & 127;
            Ch[((size_t)(bb * 8 + kvh) * 1664 + s) * 128 + d] =
                (f16)(acc[m][n][j] * rs * wv[n]);
          }
        } else {
#pragma unroll
          for (int n = 0; n < 4; ++n) {
            int col = bcol - 1024 + wn * 64 + n * 16 + lq;
            int kvh = col >> 7;
            int d = col & 127;
            Vtf[((size_t)(bb * 8 + kvh) * 128 + d) * 1664 + s] = (f16)acc[m][n][j];
          }
        }
      }
    }
  }
}

// ---------------------------------------------------------------- flash attention
// LDS-traffic-optimized: 4 waves x 32 q rows (256-thread block), KVBLK=64 --
// halves per-CU K/V ds_read amplification vs the 8-wave shape (each wave reads
// the whole K/V tile once; 4 waves instead of 8 per tile).  STATIC-MAX softmax
// (|logit| <= 16.33 bounded by RMS norms; offset -8 in MFMA C-init).
// P swizzle FIX: old ((row&7)<<4) collapsed lk in bank bits -> 4-way conflicts
// on ds_write_b16 (13.2M cycles).  New swz(row) = ((row>>2)&3)<<5 (= lk<<5 on
// write) is bijective in lk -> balanced banks on both write and pa-read.
// (256,2): 128-VGPR class; r6 measured 120 for this geometry with MORE state.
__global__ __launch_bounds__(256, 2) void attn_kernel(const f16* __restrict__ Qf,
                                                      const f16* __restrict__ Kf,
                                                      const f16* __restrict__ Vtf,
                                                      f16* __restrict__ Oa) {
  __shared__ f16 Ksm[2][64][128];  // 32 KB dbuf, 256 B rows, XOR-swizzled
  __shared__ f16 Vsm[2][128][64];  // 32 KB dbuf, V^T [d][kv], 128 B rows, swizzled
  __shared__ f16 Psm[4][32][64];   // 8 KB per-wave P, new swizzle
  const int p = blockIdx.x;              // 0..1023
  const int L = (p & 7) * 128 + (p >> 3);
  const int qt = L & 7, h = (L >> 3) & 31, b = L >> 8;
  const int kvh = h >> 2;  // G = 4
  const int tid = threadIdx.x;
  const int l = tid & 63, w = tid >> 6;  // 4 waves
  const int lq = l & 15, lk = l >> 4;

  // Q fragments: wave w owns 32 q rows (qt*128 + w*32 ..)
  f16x8 qreg[2][4];
  const f16* Qbase = Qf + ((size_t)(b * 1024 + qt * 128 + w * 32)) * 4096 + h * 128;
#pragma unroll
  for (int qm = 0; qm < 2; ++qm)
#pragma unroll
    for (int ks = 0; ks < 4; ++ks)
      qreg[qm][ks] = *reinterpret_cast<const f16x8*>(
          Qbase + (size_t)(qm * 16 + lq) * 4096 + ks * 32 + lk * 8);

  const f16* Kb = Kf + (size_t)(b * 8 + kvh) * (1664 * 128);
  const f16* Vb = Vtf + (size_t)(b * 8 + kvh) * (128 * 1664);

  f32x4 o[2][8];
  f32x4 zf = {0.f, 0.f, 0.f, 0.f};
  f32x4 neg8 = {-8.f, -8.f, -8.f, -8.f};
#pragma unroll
  for (int qm = 0; qm < 2; ++qm)
#pragma unroll
    for (int dn = 0; dn < 8; ++dn) o[qm][dn] = zf;
  float lrow[2][4];  // per-lane partial row sums, reduced once in epilogue
#pragma unroll
  for (int qm = 0; qm < 2; ++qm)
#pragma unroll
    for (int j = 0; j < 4; ++j) lrow[qm][j] = 0.f;

  char* Pw = (char*)(&Psm[w][0][0]);   // 32 rows x 128 B
  const int swzR = (lq & 7) << 4;      // K/V read swizzle (unchanged, balanced)

  auto stageK = [&](int t, int buf) {  // 16 KB over 4 waves: 4 issues, 4 rows each
#pragma unroll
    for (int i = 0; i < 4; ++i) {
      int row = w * 16 + i * 4 + lk;
      int cb = (lq * 16) ^ ((row & 7) << 4);
      gload_lds16(Kb + (size_t)(t * 64 + row) * 128 + (cb >> 1),
                  (char*)(&Ksm[buf][0][0]) + w * 4096 + i * 1024);
    }
  };
  auto stageV = [&](int t, int buf) {  // 16 KB over 4 waves: 4 issues, 8 rows each
#pragma unroll
    for (int i = 0; i < 4; ++i) {
      int r = w * 32 + i * 8 + (l >> 3);
      int cb = ((l & 7) * 16) ^ ((r & 7) << 4);
      gload_lds16(Vb + (size_t)r * 1664 + t * 64 + (cb >> 1),
                  (char*)(&Vsm[buf][0][0]) + w * 4096 + i * 1024);
    }
  };

  stageK(0, 0);
  stageV(0, 0);
  int cur = 0;
  for (int t = 0; t < 26; ++t) {
    if (t < 25) {
      stageK(t + 1, cur ^ 1);                       // 8 issues for tile t+1
      stageV(t + 1, cur ^ 1);
      asm volatile("s_waitcnt vmcnt(8)" ::: "memory");  // own tile-t loads done
    } else {
      asm volatile("s_waitcnt vmcnt(0)" ::: "memory");
    }
    __builtin_amdgcn_s_barrier();                   // all waves' tile-t loads done

    // ---- S = Q K^T - 8 (fp32 accum, static-max offset in C-init)
    f32x4 s[2][4];
#pragma unroll
    for (int qm = 0; qm < 2; ++qm)
#pragma unroll
      for (int kn = 0; kn < 4; ++kn) s[qm][kn] = neg8;
    __builtin_amdgcn_s_setprio(1);
#pragma unroll
    for (int ks = 0; ks < 4; ++ks) {
      f16x8 bf[4];
#pragma unroll
      for (int kn = 0; kn < 4; ++kn)
        bf[kn] = *reinterpret_cast<const f16x8*>(
            (char*)(&Ksm[cur][0][0]) + (kn * 16 + lq) * 256 + ((ks * 64 + lk * 16) ^ swzR));
#pragma unroll
      for (int qm = 0; qm < 2; ++qm)
#pragma unroll
        for (int kn = 0; kn < 4; ++kn)
          s[qm][kn] = __builtin_amdgcn_mfma_f32_16x16x32_f16(qreg[qm][ks], bf[kn], s[qm][kn], 0, 0, 0);
    }
    __builtin_amdgcn_s_setprio(0);

    // ---- mask tail (valid kv < 1601; tile 25 covers 1600..1663 -> local < 1)
    if (t == 25) {
#pragma unroll
      for (int kn = 0; kn < 4; ++kn) {
        bool valid = (kn * 16 + lq) < 1;
#pragma unroll
        for (int qm = 0; qm < 2; ++qm)
#pragma unroll
          for (int j = 0; j < 4; ++j) s[qm][kn][j] = valid ? s[qm][kn][j] : -1e30f;
      }
    }

    // ---- P = 2^s; per-lane partial sums; P write with conflict-free swizzle
#pragma unroll
    for (int qm = 0; qm < 2; ++qm) {
#pragma unroll
      for (int j = 0; j < 4; ++j) {
        float rsum = 0.f;
#pragma unroll
        for (int kn = 0; kn < 4; ++kn) {
          float pv = exp2f(s[qm][kn][j]);
          s[qm][kn][j] = pv;
          rsum += pv;
        }
        lrow[qm][j] += rsum;
        int prow = qm * 16 + lk * 4 + j;
        int swzW = lk << 5;  // = ((prow>>2)&3)<<5, bijective in lk
#pragma unroll
        for (int kn = 0; kn < 4; ++kn)
          *reinterpret_cast<f16*>(Pw + prow * 128 + (((kn * 16 + lq) * 2) ^ swzW)) =
              (f16)s[qm][kn][j];
      }
    }

    // ---- O += P V   (pa read uses same swizzle function of row)
    __builtin_amdgcn_s_setprio(1);
#pragma unroll
    for (int c = 0; c < 2; ++c) {
      f16x8 pa[2];
#pragma unroll
      for (int qm = 0; qm < 2; ++qm) {
        int prow = qm * 16 + lq;
        pa[qm] = *reinterpret_cast<const f16x8*>(
            Pw + prow * 128 + ((c * 64 + lk * 16) ^ (((lq >> 2) & 3) << 5)));
      }
      f16x8 vb[8];
#pragma unroll
      for (int dn = 0; dn < 8; ++dn)
        vb[dn] = *reinterpret_cast<const f16x8*>(
            (char*)(&Vsm[cur][0][0]) + (dn * 16 + lq) * 128 + ((c * 64 + lk * 16) ^ swzR));
#pragma unroll
      for (int qm = 0; qm < 2; ++qm)
#pragma unroll
        for (int dn = 0; dn < 8; ++dn)
          o[qm][dn] = __builtin_amdgcn_mfma_f32_16x16x32_f16(pa[qm], vb[dn], o[qm][dn], 0, 0, 0);
    }
    __builtin_amdgcn_s_setprio(0);
    __builtin_amdgcn_s_barrier();   // all reads of buf `cur` done before next staging
    cur ^= 1;
  }

  // ---- epilogue: reduce lrow partials across the 16-lane row group, then O/l
#pragma unroll
  for (int qm = 0; qm < 2; ++qm) {
#pragma unroll
    for (int j = 0; j < 4; ++j) {
      float fl = lrow[qm][j];
      fl += __shfl_xor(fl, 1);
      fl += __shfl_xor(fl, 2);
      fl += __shfl_xor(fl, 4);
      fl += __shfl_xor(fl, 8);
      float il = 1.0f / fl;
      int token = b * 1024 + qt * 128 + w * 32 + qm * 16 + lk * 4 + j;
      f16* dst = Oa + (size_t)token * 4096 + h * 128;
#pragma unroll
      for (int dn = 0; dn < 8; ++dn) dst[dn * 16 + lq] = (f16)(o[qm][dn][j] * il);
    }
  }
}

// ---------------------------------------------------------------- launch
extern "C" void kernel_launch(void* const* d_in, const int* in_sizes, int n_in,
                              void* d_out, int out_size, void* d_ws, size_t ws_size,
                              hipStream_t stream) {
  const float* hidden = (const float*)d_in[0];  // [4,1024,4096]
  const float* cross  = (const float*)d_in[1];  // [4,1601,4096]
  const float* wqkv   = (const float*)d_in[2];  // [6144,4096]
  const float* wo     = (const float*)d_in[3];  // [4096,4096]
  const float* qw     = (const float*)d_in[4];  // [128]
  const float* kw     = (const float*)d_in[5];  // [128]

  char* ws = (char*)d_ws;
  f16* hidden_h = (f16*)(ws + 0);            // 33.55 MB -> attn_h after Q-proj
  f16* attn_h   = hidden_h;
  f16* wqkv_h = (f16*)(ws + 33554432);       // 50.33 MB
  f16* cross_h = (f16*)(ws + 83886080);      // 52.46 MB -> wo_h after KV-proj
  f16* wo_h    = (f16*)(ws + 83886080);
  f16* k_h  = (f16*)(ws + 136347648);        // 13.63 MB
  f16* vt_h = (f16*)(ws + 136347648 + 13631488);  // 13.63 MB
  f16* q_h = (f16*)d_out;  // consumed by attn before O-proj overwrites d_out

  // 1) fused converts (hidden, cross, wqkv) + zero-fill of K/Vt pads
  cvtzero_kernel<<<2048, 256, 0, stream>>>(hidden, hidden_h, cross, cross_h,
                                           wqkv, wqkv_h, (float4*)(ws + 136347648));
  // 2) KV projection with fused K-RMS + V-transpose epilogue
  gemm256<true, 2><<<dim3(8, 26), 512, 0, stream>>>(
      cross_h, wqkv_h + (size_t)4096 * 4096, nullptr, k_h, kw, vt_h, 6404, 2048, 4096);
  // 3) wo convert (into dead cross_h region)
  cvt_kernel<<<2048, 256, 0, stream>>>(wo, wo_h, 16777216 / 4);
  // 4) Q projection with fused RMS-norm (+scale*log2e) -> f16 q_h (in d_out)
  gemm256<false, 1><<<dim3(16, 16), 512, 0, stream>>>(
      hidden_h, wqkv_h, nullptr, q_h, qw, nullptr, 4096, 4096, 4096);
  // 5) attention (4-wave blocks, grid 1024, XCD-swizzled in-kernel)
  attn_kernel<<<1024, 256, 0, stream>>>(q_h, k_h, vt_h, attn_h);
  // 6) output projection -> d_out
  gemm256<false, 0><<<dim3(16, 16), 512, 0, stream>>>(
      attn_h, wo_h, (float*)d_out, nullptr, nullptr, nullptr, 4096, 4096, 4096);
}